// Round 11
// baseline (660.790 us; speedup 1.0000x reference)
//
#include <hip/hip_runtime.h>
#include <cstdint>

// Seq2Seq GRU enc/dec with attention, batch=1, L=50, H=1024, T=128 (fp32).
// Persistent cooperative kernel, 256 WGs x 256 threads.
// Sync via VALUE TAGS (low 5 mantissa bits = epoch) + SENTINEL protocol:
// writers store payload, vmcnt(0) (manual release), then one sentinel
// element; consumers poll only sentinels (wave0), then bulk-load payload.
// This kills the poll-traffic congestion at the coherence point.
// Decoder pipeline: h -> WG0 (pinned attn rows -> aw) -> o-WGs (pinned
// M-coeffs -> o) -> producers (pinned wh+wi -> h'). Weights pinned in VGPRs
// via in-loop opaque asm (prevents rematerialization).

#define HDIM 1024
#define LSEQ 50
#define TDIM 128
#define G3   3072
#define PB   6
#define NPROD 128
#define LSTR 68

typedef float f32x4 __attribute__((ext_vector_type(4)));

struct KArgs {
  const int* input_ids; const int* tag_ids;
  const float* word_embed;
  const float* enc_Wih; const float* enc_Whh; const float* enc_bih; const float* enc_bhh;
  const float* dec_embed; const float* attn_W; const float* attn_b;
  const float* comb_W; const float* comb_b;
  const float* dec_Wih; const float* dec_Whh; const float* dec_bih; const float* dec_bhh;
  const float* out_W; const float* out_b;
  float* out;
  unsigned* ctrP; unsigned* ctrE; unsigned* ctrM; unsigned* ctrO; unsigned* ctrV;
  float* hbE;      // 2*1024 tagged
  float* hbD;      // 3*1024 tagged
  float* obD;      // 2*1024 tagged
  float* awb;      // 2*64   tagged (52 used, sentinel at 51)
  float* logits;   // 2*128  tagged
  float* GI;       // 50*3072
  float* attn_e;   // 50*50
  float* pre_comb; // 50*1024
  float* MT;       // 50*1024  (MT[s*H+i])
  float* enc_outs; // 50*1024
};

__device__ __forceinline__ void fence_vm(){
  asm volatile("s_waitcnt vmcnt(0)" ::: "memory");
}
__device__ __forceinline__ void st_coh(float* p, float v){
  __hip_atomic_store(p, v, __ATOMIC_RELAXED, __HIP_MEMORY_SCOPE_AGENT);
}
__device__ __forceinline__ void st_tag(float* p, float v, unsigned tag){
  unsigned b = (__float_as_uint(v) & ~31u) | tag;
  st_coh(p, __uint_as_float(b));
}
__device__ __forceinline__ void stf(unsigned* p, unsigned v){
  __hip_atomic_store(p, v, __ATOMIC_RELAXED, __HIP_MEMORY_SCOPE_AGENT);
}
__device__ __forceinline__ unsigned ldu(const unsigned* p){
  return __hip_atomic_load(p, __ATOMIC_RELAXED, __HIP_MEMORY_SCOPE_AGENT);
}
__device__ __forceinline__ void addc(unsigned* base, int bid){
  __hip_atomic_fetch_add(base + (bid&7)*16, 1u, __ATOMIC_RELAXED, __HIP_MEMORY_SCOPE_AGENT);
}
__device__ __forceinline__ void addc0(unsigned* base){
  __hip_atomic_fetch_add(base, 1u, __ATOMIC_RELAXED, __HIP_MEMORY_SCOPE_AGENT);
}
__device__ __forceinline__ f32x4 coh_load4(const float* p){
  f32x4 v;
  asm volatile("global_load_dwordx4 %0, %1, off sc0 sc1\n\ts_waitcnt vmcnt(0)"
               : "=v"(v) : "v"(p) : "memory");
  return v;
}
__device__ __forceinline__ float coh_load1(const float* p){
  float v;
  asm volatile("global_load_dword %0, %1, off sc0 sc1\n\ts_waitcnt vmcnt(0)"
               : "=v"(v) : "v"(p) : "memory");
  return v;
}

// ---- sentinel polls (wave0 only; tiny traffic) ----
__device__ __forceinline__ void wait_sent128(const float* g, unsigned tag, int lane){
  const float* p0 = g + 8*lane + 7;
  const float* p1 = g + 8*(lane+64) + 7;
  for(;;){
    float a,b;
    asm volatile("global_load_dword %0, %2, off sc0 sc1\n\t"
                 "global_load_dword %1, %3, off sc0 sc1\n\t"
                 "s_waitcnt vmcnt(0)"
                 : "=v"(a), "=v"(b) : "v"(p0), "v"(p1) : "memory");
    unsigned m = ((__float_as_uint(a)&31u)^tag) | ((__float_as_uint(b)&31u)^tag);
    if(__all((int)(m==0u))) return;
    __builtin_amdgcn_s_sleep(2);
  }
}
__device__ __forceinline__ void wait_sent4(const float* g, unsigned tag, int lane){
  const float* p = g + ((lane&3)<<8) + 255;
  for(;;){
    float a = coh_load1(p);
    bool ok = (lane<4)? ((__float_as_uint(a)&31u)==tag) : true;
    if(__all((int)ok)) return;
    __builtin_amdgcn_s_sleep(1);
  }
}
__device__ __forceinline__ void wait_sent1(const float* p, unsigned tag){
  for(;;){
    float a = coh_load1(p);
    if((__float_as_uint(a)&31u)==tag) return;
    __builtin_amdgcn_s_sleep(1);
  }
}

template<int N>
__device__ __forceinline__ void wred_batch(float* v){
  #pragma unroll
  for(int o=32;o>0;o>>=1){
    #pragma unroll
    for(int i=0;i<N;i++) v[i] += __shfl_xor(v[i],o,64);
  }
}
__device__ __forceinline__ float wred_sum(float v){
  #pragma unroll
  for(int o=32;o>0;o>>=1) v += __shfl_xor(v,o,64);
  return v;
}
__device__ __forceinline__ float wred_max(float v){
  #pragma unroll
  for(int o=32;o>0;o>>=1) v = fmaxf(v,__shfl_xor(v,o,64));
  return v;
}

struct Chunk { f32x4 a,b,c,d; };
__device__ __forceinline__ Chunk load_chunk(const float* __restrict__ row, int lane){
  const f32x4* p = reinterpret_cast<const f32x4*>(row) + lane*4;
  Chunk w; w.a=p[0]; w.b=p[1]; w.c=p[2]; w.d=p[3]; return w;
}
__device__ __forceinline__ void pin(Chunk& c){
  asm volatile("" : "+v"(c.a), "+v"(c.b), "+v"(c.c), "+v"(c.d));
}
__device__ __forceinline__ void pinf(float& x){
  asm volatile("" : "+v"(x));
}
__device__ __forceinline__ float chunk_dot(const Chunk& w, const float* hc){
  return w.a.x*hc[0]+w.a.y*hc[1]+w.a.z*hc[2]+w.a.w*hc[3]
       + w.b.x*hc[4]+w.b.y*hc[5]+w.b.z*hc[6]+w.b.w*hc[7]
       + w.c.x*hc[8]+w.c.y*hc[9]+w.c.z*hc[10]+w.c.w*hc[11]
       + w.d.x*hc[12]+w.d.y*hc[13]+w.d.z*hc[14]+w.d.w*hc[15];
}
__device__ __forceinline__ void load_vec16(const float* __restrict__ v, float* hc, int lane){
  const f32x4* p = reinterpret_cast<const f32x4*>(v) + lane*4;
  f32x4 x0=p[0],x1=p[1],x2=p[2],x3=p[3];
  hc[0]=x0.x; hc[1]=x0.y; hc[2]=x0.z; hc[3]=x0.w;
  hc[4]=x1.x; hc[5]=x1.y; hc[6]=x1.z; hc[7]=x1.w;
  hc[8]=x2.x; hc[9]=x2.y; hc[10]=x2.z; hc[11]=x2.w;
  hc[12]=x3.x; hc[13]=x3.y; hc[14]=x3.z; hc[15]=x3.w;
}
__device__ __forceinline__ float sigm(float x){ return 1.f/(1.f+expf(-x)); }

// one-shot bulk stage (no retry): 1024 floats -> transposed LDS
__device__ __forceinline__ void stage_fast(float* ldsb, const float* g, int tid){
  f32x4 v = coh_load4(g + 4*tid);
  int q = tid>>2, r4 = (tid&3)*4;
  ldsb[(r4+0)*LSTR+q]=v.x; ldsb[(r4+1)*LSTR+q]=v.y;
  ldsb[(r4+2)*LSTR+q]=v.z; ldsb[(r4+3)*LSTR+q]=v.w;
}
__device__ __forceinline__ void read16(const float* ldsb, float* hc, int lane){
  #pragma unroll
  for(int k=0;k<16;k++) hc[k]=ldsb[k*LSTR+lane];
}

__device__ __forceinline__ void wait8(const unsigned* base, unsigned n, int lane){
  const unsigned* p = base + lane*16;
  for(;;){
    unsigned v = (lane<8)? ldu(p) : 0xFFFFFFFFu;
    if(__all((int)(v>=n))) return;
    __builtin_amdgcn_s_sleep(8);
  }
}

__global__ __launch_bounds__(256,1) void seq2seq_kernel(KArgs A){
  const int bid = blockIdx.x, tid = threadIdx.x;
  const int wave = tid>>6, lane = tid&63;
  __shared__ float lds_h[16*LSTR+16];
  __shared__ float lds_o[16*LSTR+16];
  __shared__ float smr[64];
  __shared__ float smL[TDIM];
  __shared__ float smA[64];

  const int gv = bid*4 + wave;   // 0..1023

  // ================= prologue: token-dependent precompute ====================
  {
    const int r0 = gv*3;
    Chunk w0 = load_chunk(A.enc_Wih + (size_t)r0*HDIM, lane);
    Chunk w1 = load_chunk(A.enc_Wih + (size_t)(r0+1)*HDIM, lane);
    Chunk w2 = load_chunk(A.enc_Wih + (size_t)(r0+2)*HDIM, lane);
    float b0=A.enc_bih[r0], b1=A.enc_bih[r0+1], b2=A.enc_bih[r0+2];
    for(int te=0;te<LSEQ;++te){
      int tok = A.input_ids[te];
      float ec[16]; load_vec16(A.word_embed + (size_t)tok*HDIM, ec, lane);
      float d[3];
      d[0]=chunk_dot(w0,ec); d[1]=chunk_dot(w1,ec); d[2]=chunk_dot(w2,ec);
      wred_batch<3>(d);
      if(lane==0){
        st_coh(&A.GI[te*G3+r0],   d[0]+b0);
        st_coh(&A.GI[te*G3+r0+1], d[1]+b1);
        st_coh(&A.GI[te*G3+r0+2], d[2]+b2);
      }
    }
    Chunk wc = load_chunk(A.comb_W + (size_t)gv*2*HDIM, lane);
    float bc = A.comb_b[gv];
    Chunk wa; wa.a=0.f; wa.b=0.f; wa.c=0.f; wa.d=0.f;
    float ba = 0.f;
    if(gv < LSEQ){ wa = load_chunk(A.attn_W + (size_t)gv*2*HDIM, lane); ba = A.attn_b[gv]; }
    for(int t=0;t<LSEQ;++t){
      int tok = (t==0)?1:A.tag_ids[t-1];
      float ec[16]; load_vec16(A.dec_embed + (size_t)tok*HDIM, ec, lane);
      float d[2];
      d[0]=chunk_dot(wc,ec);
      d[1]=(gv<LSEQ)? chunk_dot(wa,ec) : 0.f;
      wred_batch<2>(d);
      if(lane==0){
        st_coh(&A.pre_comb[t*HDIM+gv], d[0]+bc);
        if(gv<LSEQ) st_coh(&A.attn_e[t*LSEQ+gv], d[1]+ba);
      }
    }
  }
  fence_vm();
  __syncthreads();
  if(tid==0) addc(A.ctrP, bid);
  if(wave==0) wait8(A.ctrP, 32u, lane);
  __syncthreads();

  // producer geometry: bids 6..133 own 8 h-elements each
  const int p = bid - PB;
  const bool is_prod = (p>=0 && p<NPROD);
  const int base = is_prod ? p*8 : 0;
  const int j8 = base + (tid&7);

  // ================= encoder: 50 sequential GRU steps (producers) ===========
  if(is_prod){
    Chunk we[6];
    #pragma unroll
    for(int i=0;i<6;i++){
      int r = wave + 4*i;                 // r = 3*le + g
      int le=r/3, g=r-3*le, row=g*HDIM+base+le;
      we[i] = load_chunk(A.enc_Whh + (size_t)row*HDIM, lane);
    }
    float bh0=A.enc_bhh[j8], bh1=A.enc_bhh[HDIM+j8], bh2=A.enc_bhh[2*HDIM+j8];
    for(int te=0;te<LSEQ;++te){
      #pragma unroll
      for(int i=0;i<6;i++) pin(we[i]);    // force loop-carried residency
      const float* GIr = A.GI + te*G3;
      float gi0=GIr[j8], gi1=GIr[HDIM+j8], gi2=GIr[2*HDIM+j8];
      float hc[16];
      if(te>0){
        if(wave==0) wait_sent128(A.hbE + ((te-1)&1)*HDIM, (unsigned)(te&31), lane);
        __syncthreads();
        stage_fast(lds_h, A.hbE + ((te-1)&1)*HDIM, tid);
        __syncthreads();
        read16(lds_h, hc, lane);
      } else {
        for(int k=0;k<16;k++) hc[k]=0.f;
      }
      float part[6];
      #pragma unroll
      for(int i=0;i<6;i++) part[i]=chunk_dot(we[i],hc);
      wred_batch<6>(part);
      if(lane==0){
        #pragma unroll
        for(int i=0;i<6;i++) smr[wave+4*i]=part[i];
      }
      __syncthreads();
      float h2=0.f; int j=0;
      if(tid<8){
        j = base+tid;
        float gr=smr[tid*3]+bh0, gz=smr[tid*3+1]+bh1, gn=smr[tid*3+2]+bh2;
        float hj = (te>0)? lds_h[((j&15)*LSTR)+(j>>4)] : 0.f;
        float r_=sigm(gi0+gr), z_=sigm(gi1+gz);
        float n_=tanhf(gi2+r_*gn);
        h2=(1.f-z_)*n_+z_*hj;
        st_coh(&A.enc_outs[te*HDIM+j], h2);
        if(tid<7){
          st_tag(&A.hbE[(te&1)*HDIM+j], h2, (unsigned)((te+1)&31));
          if(te==LSEQ-1) st_tag(&A.hbD[j], h2, 0u);
        }
      }
      fence_vm();                          // release: payload before sentinel
      if(tid==7){
        st_tag(&A.hbE[(te&1)*HDIM+j], h2, (unsigned)((te+1)&31));
        if(te==LSEQ-1) st_tag(&A.hbD[j], h2, 0u);
      }
      __syncthreads();
    }
    fence_vm();
    __syncthreads();
    if(tid==0) addc(A.ctrE, bid);
  }
  if(wave==0) wait8(A.ctrE, 16u, lane);   // 128 producers -> 16 per class
  __syncthreads();

  // ================= MT = comb_W[:,H:] @ enc_outs^T ==========================
  {
    Chunk wm = load_chunk(A.comb_W + (size_t)gv*2*HDIM + HDIM, lane);
    for(int sg=0;sg<10;++sg){
      float pt[5];
      #pragma unroll
      for(int j=0;j<5;j++){
        float ec[16]; load_vec16(A.enc_outs + (sg*5+j)*HDIM, ec, lane);
        pt[j]=chunk_dot(wm,ec);
      }
      wred_batch<5>(pt);
      if(lane==0){
        #pragma unroll
        for(int j=0;j<5;j++) st_coh(&A.MT[(sg*5+j)*HDIM+gv], pt[j]);
      }
    }
  }
  fence_vm();
  __syncthreads();
  if(tid==0) addc(A.ctrM, bid);
  {
    const bool keep = is_prod || bid==0 || bid==4 ||
                      (bid>=134 && bid<154);
    if(!keep) return;                      // spectators done
  }
  if(wave==0) wait8(A.ctrM, 32u, lane);
  __syncthreads();

  // ================= decoder: 50 steps, pipelined specialists ================
  if(bid == 0){
    // attn WG: 13 pinned attn_W[:,H:] chunks per wave (s = wave+4*i)
    Chunk wa13[13];
    int srow[13];
    #pragma unroll
    for(int i=0;i<13;i++){
      int s = wave + 4*i; int sc = (s<LSEQ)? s : 0;
      wa13[i] = load_chunk(A.attn_W + (size_t)sc*2*HDIM + HDIM, lane);
      srow[i] = s;
    }
    for(int t=0;t<LSEQ;++t){
      #pragma unroll
      for(int i=0;i<13;i++) pin(wa13[i]);
      const unsigned tg = (unsigned)(t&31);
      float ae[13];
      #pragma unroll
      for(int i=0;i<13;i++)
        ae[i] = (srow[i]<LSEQ)? A.attn_e[t*LSEQ+srow[i]] : 0.f;
      if(wave==0) wait_sent128(A.hbD + (t%3)*HDIM, tg, lane);
      __syncthreads();
      stage_fast(lds_h, A.hbD + (t%3)*HDIM, tid);
      __syncthreads();
      float hc[16]; read16(lds_h, hc, lane);
      float pl[13];
      #pragma unroll
      for(int i=0;i<13;i++) pl[i]=chunk_dot(wa13[i],hc);
      wred_batch<13>(pl);
      if(lane==0){
        #pragma unroll
        for(int i=0;i<13;i++) if(srow[i]<LSEQ) smL[srow[i]]=pl[i]+ae[i];
      }
      __syncthreads();
      float av=0.f;
      if(wave==0){
        float l = (lane<LSEQ)? smL[lane] : -1e30f;
        float m = wred_max(l);
        float pe = (lane<LSEQ)? expf(l-m) : 0.f;
        float ss = wred_sum(pe);
        av = (lane<LSEQ)? pe/ss : 0.f;
        if(lane<51) st_tag(&A.awb[(t&1)*64+lane], av, tg);
      }
      fence_vm();                           // release before aw sentinel
      if(wave==0 && lane==51) st_tag(&A.awb[(t&1)*64+51], av, tg);
      __syncthreads();
    }
  } else if(bid>=150 && bid<154){
    // o-WGs: thread owns o[i]; 50 M coefficients pinned in VGPRs
    const int i = (bid-150)*256 + tid;
    float m50[50];
    #pragma unroll
    for(int s=0;s<LSEQ;s++) m50[s]=A.MT[s*HDIM+i];
    for(int t=0;t<LSEQ;++t){
      #pragma unroll
      for(int s=0;s<LSEQ;s++) pinf(m50[s]);
      const unsigned tg = (unsigned)(t&31);
      float pcv = A.pre_comb[t*HDIM+i];
      if(wave==0) wait_sent1(A.awb + (t&1)*64 + 51, tg);
      __syncthreads();
      if(tid<13){
        f32x4 v = coh_load4(A.awb + (t&1)*64 + 4*tid);
        smA[4*tid]=v.x; smA[4*tid+1]=v.y; smA[4*tid+2]=v.z; smA[4*tid+3]=v.w;
      }
      __syncthreads();
      float acc = pcv;
      #pragma unroll
      for(int s=0;s<LSEQ;s++) acc = fmaf(m50[s], smA[s], acc);
      float ov = fmaxf(acc,0.f);
      if(tid<255) st_tag(&A.obD[(t&1)*HDIM+i], ov, tg);
      fence_vm();
      __syncthreads();                      // all waves' payload released
      if(tid==255) st_tag(&A.obD[(t&1)*HDIM+i], ov, tg);
      __syncthreads();
    }
  } else if(bid == 4){
    // collect tagged logits, double log_softmax, out + loss
    float loss = 0.f;
    for(int t=0;t<LSEQ;++t){
      if(tid<32){
        const float* pp = A.logits + (t&1)*TDIM + 4*tid;
        const unsigned tg = (unsigned)(t&31);
        f32x4 v;
        for(;;){
          v = coh_load4(pp);
          unsigned m = ((__float_as_uint(v.x)&31u)^tg) | ((__float_as_uint(v.y)&31u)^tg)
                     | ((__float_as_uint(v.z)&31u)^tg) | ((__float_as_uint(v.w)&31u)^tg);
          if(m==0u) break;
          __builtin_amdgcn_s_sleep(2);
        }
        smL[4*tid]=v.x; smL[4*tid+1]=v.y; smL[4*tid+2]=v.z; smL[4*tid+3]=v.w;
      }
      __syncthreads();
      if(tid==0) stf(A.ctrV, (unsigned)(t+1));   // epoch t logits consumed
      if(wave==0){
        float l0=smL[lane], l1=smL[lane+64];
        float m  = wred_max(fmaxf(l0,l1));
        float pe = expf(l0-m)+expf(l1-m);
        float s1 = wred_sum(pe);
        float lse = m + logf(s1);
        float lp0 = l0-lse, lp1 = l1-lse;
        float m2  = wred_max(fmaxf(lp0,lp1));
        float p2  = expf(lp0-m2)+expf(lp1-m2);
        float s2  = wred_sum(p2);
        float lse2 = m2 + logf(s2);
        A.out[t*TDIM + lane]      = lp0;
        A.out[t*TDIM + 64 + lane] = lp1;
        int tg2 = A.tag_ids[t];
        float c = ((lane==tg2)?(lse2-lp0):0.f) + ((lane+64==tg2)?(lse2-lp1):0.f);
        c = wred_sum(c);
        if(tg2 != 0) loss += c;
      }
      __syncthreads();
    }
    if(tid==0) A.out[LSEQ*TDIM] = loss;
  } else if(is_prod){
    // producers: pinned wh + wi; stage h -> gh -> stage o -> gi -> combine
    Chunk wh[6], wi[6];
    #pragma unroll
    for(int i=0;i<6;i++){
      int r = wave + 4*i;
      int le=r/3, g=r-3*le, row=g*HDIM+base+le;
      wh[i] = load_chunk(A.dec_Whh + (size_t)row*HDIM, lane);
      wi[i] = load_chunk(A.dec_Wih + (size_t)row*HDIM, lane);
    }
    float dh0=A.dec_bhh[j8], dh1=A.dec_bhh[HDIM+j8], dh2=A.dec_bhh[2*HDIM+j8];
    float di0=A.dec_bih[j8], di1=A.dec_bih[HDIM+j8], di2=A.dec_bih[2*HDIM+j8];
    for(int t=0;t<LSEQ;++t){
      #pragma unroll
      for(int i=0;i<6;i++){ pin(wh[i]); pin(wi[i]); }
      const unsigned tg = (unsigned)(t&31);
      if(wave==0) wait_sent128(A.hbD + (t%3)*HDIM, tg, lane);
      __syncthreads();
      stage_fast(lds_h, A.hbD + (t%3)*HDIM, tid);
      __syncthreads();
      float hc[16]; read16(lds_h, hc, lane);
      float ph[6];
      #pragma unroll
      for(int i=0;i<6;i++) ph[i]=chunk_dot(wh[i],hc);
      wred_batch<6>(ph);
      if(lane==0){
        #pragma unroll
        for(int i=0;i<6;i++) smr[wave+4*i]=ph[i];
      }
      // gate: out-proj WGs must have staged epoch t-2 before we clobber hbD
      if(wave==0 && t>=3){
        const unsigned tgt = 16u*(unsigned)(t-2);
        for(;;){
          unsigned v = (lane==0)? ldu(A.ctrO) : tgt;
          if(__all((int)(v>=tgt))) break;
          __builtin_amdgcn_s_sleep(2);
        }
      }
      if(wave==0) wait_sent4(A.obD + (t&1)*HDIM, tg, lane);
      __syncthreads();
      stage_fast(lds_o, A.obD + (t&1)*HDIM, tid);
      __syncthreads();
      float oc[16]; read16(lds_o, oc, lane);
      float po[6];
      #pragma unroll
      for(int i=0;i<6;i++) po[i]=chunk_dot(wi[i],oc);
      wred_batch<6>(po);
      if(lane==0){
        #pragma unroll
        for(int i=0;i<6;i++) smr[32+wave+4*i]=po[i];
      }
      __syncthreads();
      float h2=0.f; int j=0;
      if(tid<8){
        j = base+tid;
        float gr=smr[tid*3]+dh0,    gz=smr[tid*3+1]+dh1,    gn=smr[tid*3+2]+dh2;
        float ir=smr[32+tid*3]+di0, iz=smr[32+tid*3+1]+di1, inn=smr[32+tid*3+2]+di2;
        float hj = lds_h[((j&15)*LSTR)+(j>>4)];
        float r_=sigm(ir+gr), z_=sigm(iz+gz);
        float n_=tanhf(inn+r_*gn);
        h2=(1.f-z_)*n_+z_*hj;
        if(tid<7) st_tag(&A.hbD[((t+1)%3)*HDIM+j], h2, (unsigned)((t+1)&31));
      }
      fence_vm();                          // release payload before sentinel
      if(tid==7) st_tag(&A.hbD[((t+1)%3)*HDIM+j], h2, (unsigned)((t+1)&31));
      __syncthreads();
    }
  } else {
    // out-proj: bids 134..149, 8 rows each, 2 rows/wave pinned in VGPRs
    const int ob = bid-134;
    Chunk wo[2];
    float bo[2];
    #pragma unroll
    for(int i=0;i<2;i++){
      int row = ob*8 + wave*2 + i;
      wo[i]=load_chunk(A.out_W+(size_t)row*HDIM,lane);
      bo[i]=A.out_b[row];
    }
    for(int t=0;t<LSEQ;++t){
      pin(wo[0]); pin(wo[1]);
      const unsigned tg1 = (unsigned)((t+1)&31);
      if(wave==0) wait_sent128(A.hbD + ((t+1)%3)*HDIM, tg1, lane);
      __syncthreads();
      stage_fast(lds_h, A.hbD + ((t+1)%3)*HDIM, tid);
      __syncthreads();
      if(tid==0) addc0(A.ctrO);            // "I staged epoch t+1"
      float hc[16]; read16(lds_h, hc, lane);
      float pt[2]={chunk_dot(wo[0],hc),chunk_dot(wo[1],hc)};
      wred_batch<2>(pt);
      if(wave==0 && t>=2){
        const unsigned tgt = (unsigned)(t-1);  // WG4 consumed epoch t-2
        for(;;){
          unsigned v = (lane==0)? ldu(A.ctrV) : tgt;
          if(__all((int)(v>=tgt))) break;
          __builtin_amdgcn_s_sleep(4);
        }
      }
      __syncthreads();
      if(lane==0){
        int row = ob*8 + wave*2;
        st_tag(&A.logits[(t&1)*TDIM + row],   pt[0]+bo[0], (unsigned)(t&31));
        st_tag(&A.logits[(t&1)*TDIM + row+1], pt[1]+bo[1], (unsigned)(t&31));
      }
      __syncthreads();
    }
  }
}

extern "C" void kernel_launch(void* const* d_in, const int* in_sizes, int n_in,
                              void* d_out, int out_size, void* d_ws, size_t ws_size,
                              hipStream_t stream){
  (void)in_sizes; (void)n_in; (void)out_size; (void)ws_size;
  KArgs A;
  A.input_ids = (const int*)d_in[0];
  A.tag_ids   = (const int*)d_in[1];
  A.word_embed= (const float*)d_in[2];
  A.enc_Wih   = (const float*)d_in[3];
  A.enc_Whh   = (const float*)d_in[4];
  A.enc_bih   = (const float*)d_in[5];
  A.enc_bhh   = (const float*)d_in[6];
  A.dec_embed = (const float*)d_in[7];
  A.attn_W    = (const float*)d_in[8];
  A.attn_b    = (const float*)d_in[9];
  A.comb_W    = (const float*)d_in[10];
  A.comb_b    = (const float*)d_in[11];
  A.dec_Wih   = (const float*)d_in[12];
  A.dec_Whh   = (const float*)d_in[13];
  A.dec_bih   = (const float*)d_in[14];
  A.dec_bhh   = (const float*)d_in[15];
  A.out_W     = (const float*)d_in[16];
  A.out_b     = (const float*)d_in[17];
  A.out       = (float*)d_out;

  unsigned* u = (unsigned*)d_ws;
  A.ctrP = u;          // 8 lines (stride 16u)
  A.ctrE = u + 128;
  A.ctrM = u + 256;
  A.ctrO = u + 384;    // single line
  A.ctrV = u + 448;    // single line
  float* f = (float*)d_ws + 1024;   // byte 4096, tagged region start
  A.hbE    = f; f += 2*HDIM;
  A.hbD    = f; f += 3*HDIM;
  A.obD    = f; f += 2*HDIM;
  A.awb    = f; f += 2*64;
  A.logits = f; f += 2*TDIM;        // tagged region: 7552 floats
  A.GI       = f; f += LSEQ*G3;
  A.attn_e   = f; f += LSEQ*LSEQ + 14;
  A.pre_comb = f; f += LSEQ*HDIM;
  A.MT       = f; f += LSEQ*HDIM;
  A.enc_outs = f; f += LSEQ*HDIM;

  (void)hipMemsetAsync(d_ws, 0, 4096, stream);                        // counters
  (void)hipMemsetAsync((char*)d_ws + 4096, 0xFF, 7552*4, stream);     // tag bufs -> tag 31
  void* args[] = { &A };
  hipError_t err = hipLaunchCooperativeKernel((const void*)seq2seq_kernel,
                                              dim3(256), dim3(256), args, 0, stream);
  if(err != hipSuccess){
    // 256 WGs on 256 CUs are co-resident by capacity; cooperative API was
    // only belt-and-braces. Fall back to a normal launch.
    hipLaunchKernelGGL(seq2seq_kernel, dim3(256), dim3(256), 0, stream, A);
  }
}

// Round 12
// 511.177 us; speedup vs baseline: 1.2927x; 1.2927x over previous
//
#include <hip/hip_runtime.h>
#include <cstdint>

// Seq2Seq GRU enc/dec with attention, batch=1, L=50, H=1024, T=128 (fp32 in/out).
// Persistent cooperative kernel, 256 WGs x 256 threads.
// Sync: VALUE TAGS (low 5 mantissa bits = epoch); consumer retry loads ARE the
// poll (R9 protocol — R11's sentinel split each hop into 2 RTs and regressed).
// NEW: weights held as fp16-packed pairs in VGPRs (fits -> no scratch spills;
// v_dot2_f32_f16 doubles dot rate). Decoder = 2 hops: h -> o-WGs (redundant
// pinned attn + pinned M -> aw,o) -> producers (pinned wh+wi -> h').

#define HDIM 1024
#define LSEQ 50
#define TDIM 128
#define G3   3072
#define PB   6
#define NPROD 128
#define LSTRP 65

typedef float f32x4 __attribute__((ext_vector_type(4)));
typedef _Float16 h2 __attribute__((ext_vector_type(2)));

#if __has_builtin(__builtin_amdgcn_fdot2)
#define FDOT2(a,b,c) __builtin_amdgcn_fdot2((a),(b),(c),false)
#else
__device__ __forceinline__ float fdot2_sw(h2 a, h2 b, float c){
  return c + (float)a[0]*(float)b[0] + (float)a[1]*(float)b[1];
}
#define FDOT2(a,b,c) fdot2_sw((a),(b),(c))
#endif

struct KArgs {
  const int* input_ids; const int* tag_ids;
  const float* word_embed;
  const float* enc_Wih; const float* enc_Whh; const float* enc_bih; const float* enc_bhh;
  const float* dec_embed; const float* attn_W; const float* attn_b;
  const float* comb_W; const float* comb_b;
  const float* dec_Wih; const float* dec_Whh; const float* dec_bih; const float* dec_bhh;
  const float* out_W; const float* out_b;
  float* out;
  unsigned* ctrP; unsigned* ctrE; unsigned* ctrM; unsigned* ctrO; unsigned* ctrV;
  float* hbE;      // 2*1024 tagged
  float* hbD;      // 3*1024 tagged
  float* obD;      // 2*1024 tagged
  float* logits;   // 2*128  tagged
  float* GI;       // 50*3072
  float* attn_e;   // 50*50
  float* pre_comb; // 50*1024
  float* MT;       // 50*1024  (MT[s*H+i])
  float* enc_outs; // 50*1024
};

__device__ __forceinline__ void fence_vm(){
  asm volatile("s_waitcnt vmcnt(0)" ::: "memory");
}
__device__ __forceinline__ void st_coh(float* p, float v){
  __hip_atomic_store(p, v, __ATOMIC_RELAXED, __HIP_MEMORY_SCOPE_AGENT);
}
__device__ __forceinline__ void st_tag(float* p, float v, unsigned tag){
  unsigned b = (__float_as_uint(v) & ~31u) | tag;
  st_coh(p, __uint_as_float(b));
}
__device__ __forceinline__ void stf(unsigned* p, unsigned v){
  __hip_atomic_store(p, v, __ATOMIC_RELAXED, __HIP_MEMORY_SCOPE_AGENT);
}
__device__ __forceinline__ unsigned ldu(const unsigned* p){
  return __hip_atomic_load(p, __ATOMIC_RELAXED, __HIP_MEMORY_SCOPE_AGENT);
}
__device__ __forceinline__ void addc(unsigned* base, int bid){
  __hip_atomic_fetch_add(base + (bid&7)*16, 1u, __ATOMIC_RELAXED, __HIP_MEMORY_SCOPE_AGENT);
}
__device__ __forceinline__ void addc0(unsigned* base){
  __hip_atomic_fetch_add(base, 1u, __ATOMIC_RELAXED, __HIP_MEMORY_SCOPE_AGENT);
}
__device__ __forceinline__ f32x4 coh_load4(const float* p){
  f32x4 v;
  asm volatile("global_load_dwordx4 %0, %1, off sc0 sc1\n\ts_waitcnt vmcnt(0)"
               : "=v"(v) : "v"(p) : "memory");
  return v;
}

template<int N>
__device__ __forceinline__ void wred_batch(float* v){
  #pragma unroll
  for(int o=32;o>0;o>>=1){
    #pragma unroll
    for(int i=0;i<N;i++) v[i] += __shfl_xor(v[i],o,64);
  }
}
__device__ __forceinline__ float wred_sum(float v){
  #pragma unroll
  for(int o=32;o>0;o>>=1) v += __shfl_xor(v,o,64);
  return v;
}
__device__ __forceinline__ float wred_max(float v){
  #pragma unroll
  for(int o=32;o>0;o>>=1) v = fmaxf(v,__shfl_xor(v,o,64));
  return v;
}

// ---- fp32 chunk machinery (prologue / MT only) ----
struct Chunk { f32x4 a,b,c,d; };
__device__ __forceinline__ Chunk load_chunk(const float* __restrict__ row, int lane){
  const f32x4* p = reinterpret_cast<const f32x4*>(row) + lane*4;
  Chunk w; w.a=p[0]; w.b=p[1]; w.c=p[2]; w.d=p[3]; return w;
}
__device__ __forceinline__ float chunk_dot(const Chunk& w, const float* hc){
  return w.a.x*hc[0]+w.a.y*hc[1]+w.a.z*hc[2]+w.a.w*hc[3]
       + w.b.x*hc[4]+w.b.y*hc[5]+w.b.z*hc[6]+w.b.w*hc[7]
       + w.c.x*hc[8]+w.c.y*hc[9]+w.c.z*hc[10]+w.c.w*hc[11]
       + w.d.x*hc[12]+w.d.y*hc[13]+w.d.z*hc[14]+w.d.w*hc[15];
}
__device__ __forceinline__ void load_vec16(const float* __restrict__ v, float* hc, int lane){
  const f32x4* p = reinterpret_cast<const f32x4*>(v) + lane*4;
  f32x4 x0=p[0],x1=p[1],x2=p[2],x3=p[3];
  hc[0]=x0.x; hc[1]=x0.y; hc[2]=x0.z; hc[3]=x0.w;
  hc[4]=x1.x; hc[5]=x1.y; hc[6]=x1.z; hc[7]=x1.w;
  hc[8]=x2.x; hc[9]=x2.y; hc[10]=x2.z; hc[11]=x2.w;
  hc[12]=x3.x; hc[13]=x3.y; hc[14]=x3.z; hc[15]=x3.w;
}

// ---- fp16-packed row chunk: 16 weights as 8 packed pairs (8 VGPRs) ----
struct PChunk { unsigned m[8]; };
__device__ __forceinline__ h2 as_h2(unsigned u){ return __builtin_bit_cast(h2, u); }
__device__ __forceinline__ unsigned as_u(h2 h){ return __builtin_bit_cast(unsigned, h); }
__device__ __forceinline__ unsigned pack2(float a, float b){
  return as_u((h2){(_Float16)a, (_Float16)b});
}
__device__ __forceinline__ PChunk load_pchunk(const float* __restrict__ row, int lane){
  const f32x4* p = reinterpret_cast<const f32x4*>(row) + lane*4;
  f32x4 a=p[0],b=p[1],c=p[2],d=p[3];
  PChunk w;
  w.m[0]=pack2(a.x,a.y); w.m[1]=pack2(a.z,a.w);
  w.m[2]=pack2(b.x,b.y); w.m[3]=pack2(b.z,b.w);
  w.m[4]=pack2(c.x,c.y); w.m[5]=pack2(c.z,c.w);
  w.m[6]=pack2(d.x,d.y); w.m[7]=pack2(d.z,d.w);
  return w;
}
__device__ __forceinline__ void pinp(PChunk& c){
  asm volatile("" : "+v"(c.m[0]),"+v"(c.m[1]),"+v"(c.m[2]),"+v"(c.m[3]),
                    "+v"(c.m[4]),"+v"(c.m[5]),"+v"(c.m[6]),"+v"(c.m[7]));
}
__device__ __forceinline__ void pin32(unsigned& x){ asm volatile("" : "+v"(x)); }
__device__ __forceinline__ float pdot(const PChunk& w, const h2* hp){
  float acc = 0.f;
  #pragma unroll
  for(int k=0;k<8;k++) acc = FDOT2(as_h2(w.m[k]), hp[k], acc);
  return acc;
}
__device__ __forceinline__ float sigm(float x){ return 1.f/(1.f+expf(-x)); }

// retry-stage 1024 tagged fp32 -> packed fp16 LDS. Element j lives in pair
// pj=j>>1 at ldsp[(pj&7)*LSTRP + (pj>>3)]. Retry until all 4 tags match.
template<int SLP>
__device__ __forceinline__ void stage_tag_p(h2* ldsp, const float* g, int tid, unsigned tag){
  const float* p = g + 4*tid;
  f32x4 v;
  for(;;){
    v = coh_load4(p);
    unsigned m = ((__float_as_uint(v.x)&31u)^tag) | ((__float_as_uint(v.y)&31u)^tag)
               | ((__float_as_uint(v.z)&31u)^tag) | ((__float_as_uint(v.w)&31u)^tag);
    if(m==0u) break;
    if(SLP) __builtin_amdgcn_s_sleep(SLP);
  }
  int q = tid>>2, m0 = (tid&3)*2;
  ldsp[m0*LSTRP+q]     = (h2){(_Float16)v.x,(_Float16)v.y};
  ldsp[(m0+1)*LSTRP+q] = (h2){(_Float16)v.z,(_Float16)v.w};
}
__device__ __forceinline__ void read8p(const h2* ldsp, h2* hp, int lane){
  #pragma unroll
  for(int k=0;k<8;k++) hp[k]=ldsp[k*LSTRP+lane];
}
__device__ __forceinline__ float hread(const h2* ldsp, int j){
  int pj = j>>1;
  h2 v = ldsp[(pj&7)*LSTRP + (pj>>3)];
  return (float)v[j&1];
}

__device__ __forceinline__ void wait8(const unsigned* base, unsigned n, int lane){
  const unsigned* p = base + lane*16;
  for(;;){
    unsigned v = (lane<8)? ldu(p) : 0xFFFFFFFFu;
    if(__all((int)(v>=n))) return;
    __builtin_amdgcn_s_sleep(8);
  }
}

__global__ __launch_bounds__(256,1) void seq2seq_kernel(KArgs A){
  const int bid = blockIdx.x, tid = threadIdx.x;
  const int wave = tid>>6, lane = tid&63;
  __shared__ h2 ldsp_h[8*LSTRP+8];
  __shared__ h2 ldsp_o[8*LSTRP+8];
  __shared__ h2 awpL[32];
  __shared__ float smr[64];
  __shared__ float smL[TDIM];
  __shared__ float smA[64];

  const int gv = bid*4 + wave;   // 0..1023

  // ================= prologue: token-dependent precompute (fp32) ============
  {
    const int r0 = gv*3;
    Chunk w0 = load_chunk(A.enc_Wih + (size_t)r0*HDIM, lane);
    Chunk w1 = load_chunk(A.enc_Wih + (size_t)(r0+1)*HDIM, lane);
    Chunk w2 = load_chunk(A.enc_Wih + (size_t)(r0+2)*HDIM, lane);
    float b0=A.enc_bih[r0], b1=A.enc_bih[r0+1], b2=A.enc_bih[r0+2];
    for(int te=0;te<LSEQ;++te){
      int tok = A.input_ids[te];
      float ec[16]; load_vec16(A.word_embed + (size_t)tok*HDIM, ec, lane);
      float d[3];
      d[0]=chunk_dot(w0,ec); d[1]=chunk_dot(w1,ec); d[2]=chunk_dot(w2,ec);
      wred_batch<3>(d);
      if(lane==0){
        st_coh(&A.GI[te*G3+r0],   d[0]+b0);
        st_coh(&A.GI[te*G3+r0+1], d[1]+b1);
        st_coh(&A.GI[te*G3+r0+2], d[2]+b2);
      }
    }
    Chunk wc = load_chunk(A.comb_W + (size_t)gv*2*HDIM, lane);
    float bc = A.comb_b[gv];
    Chunk wa; wa.a=0.f; wa.b=0.f; wa.c=0.f; wa.d=0.f;
    float ba = 0.f;
    if(gv < LSEQ){ wa = load_chunk(A.attn_W + (size_t)gv*2*HDIM, lane); ba = A.attn_b[gv]; }
    for(int t=0;t<LSEQ;++t){
      int tok = (t==0)?1:A.tag_ids[t-1];
      float ec[16]; load_vec16(A.dec_embed + (size_t)tok*HDIM, ec, lane);
      float d[2];
      d[0]=chunk_dot(wc,ec);
      d[1]=(gv<LSEQ)? chunk_dot(wa,ec) : 0.f;
      wred_batch<2>(d);
      if(lane==0){
        st_coh(&A.pre_comb[t*HDIM+gv], d[0]+bc);
        if(gv<LSEQ) st_coh(&A.attn_e[t*LSEQ+gv], d[1]+ba);
      }
    }
  }
  fence_vm();
  __syncthreads();
  if(tid==0) addc(A.ctrP, bid);
  if(wave==0) wait8(A.ctrP, 32u, lane);
  __syncthreads();

  // producer geometry: bids 6..133 own 8 h-elements each
  const int p = bid - PB;
  const bool is_prod = (p>=0 && p<NPROD);
  const int base = is_prod ? p*8 : 0;
  const int j8 = base + (tid&7);

  // ================= encoder: 50 sequential GRU steps (producers) ===========
  if(is_prod){
    PChunk wep[6];
    #pragma unroll
    for(int i=0;i<6;i++){
      int r = wave + 4*i;                 // r = 3*le + g
      int le=r/3, g=r-3*le, row=g*HDIM+base+le;
      wep[i] = load_pchunk(A.enc_Whh + (size_t)row*HDIM, lane);
      pinp(wep[i]);
    }
    float bh0=A.enc_bhh[j8], bh1=A.enc_bhh[HDIM+j8], bh2=A.enc_bhh[2*HDIM+j8];
    for(int te=0;te<LSEQ;++te){
      const float* GIr = A.GI + te*G3;
      float gi0=GIr[j8], gi1=GIr[HDIM+j8], gi2=GIr[2*HDIM+j8];
      h2 hp[8];
      if(te>0){
        stage_tag_p<1>(ldsp_h, A.hbE + ((te-1)&1)*HDIM, tid, (unsigned)(te&31));
        __syncthreads();
        read8p(ldsp_h, hp, lane);
      } else {
        #pragma unroll
        for(int k=0;k<8;k++) hp[k]=(h2){(_Float16)0.f,(_Float16)0.f};
      }
      float part[6];
      #pragma unroll
      for(int i=0;i<6;i++) part[i]=pdot(wep[i],hp);
      wred_batch<6>(part);
      if(lane==0){
        #pragma unroll
        for(int i=0;i<6;i++) smr[wave+4*i]=part[i];
      }
      __syncthreads();
      if(tid<8){
        int j = base+tid;
        float gr=smr[tid*3]+bh0, gz=smr[tid*3+1]+bh1, gn=smr[tid*3+2]+bh2;
        float hj = (te>0)? hread(ldsp_h, j) : 0.f;
        float r_=sigm(gi0+gr), z_=sigm(gi1+gz);
        float n_=tanhf(gi2+r_*gn);
        float h2v=(1.f-z_)*n_+z_*hj;
        st_tag(&A.hbE[(te&1)*HDIM+j], h2v, (unsigned)((te+1)&31));
        st_coh(&A.enc_outs[te*HDIM+j], h2v);
        if(te==LSEQ-1) st_tag(&A.hbD[j], h2v, 0u);
      }
      __syncthreads();
    }
    fence_vm();
    __syncthreads();
    if(tid==0) addc(A.ctrE, bid);
  }
  if(wave==0) wait8(A.ctrE, 16u, lane);   // 128 producers -> 16 per class
  __syncthreads();

  // ================= MT = comb_W[:,H:] @ enc_outs^T (fp32) ==================
  {
    Chunk wm = load_chunk(A.comb_W + (size_t)gv*2*HDIM + HDIM, lane);
    for(int sg=0;sg<10;++sg){
      float pt[5];
      #pragma unroll
      for(int j=0;j<5;j++){
        float ec[16]; load_vec16(A.enc_outs + (sg*5+j)*HDIM, ec, lane);
        pt[j]=chunk_dot(wm,ec);
      }
      wred_batch<5>(pt);
      if(lane==0){
        #pragma unroll
        for(int j=0;j<5;j++) st_coh(&A.MT[(sg*5+j)*HDIM+gv], pt[j]);
      }
    }
  }
  fence_vm();
  __syncthreads();
  if(tid==0) addc(A.ctrM, bid);
  {
    const bool keep = is_prod || bid<5 || (bid>=134 && bid<150);
    if(!keep) return;                      // spectators done
  }
  if(wave==0) wait8(A.ctrM, 32u, lane);
  __syncthreads();

  // ================= decoder: 50 steps, 2 hops ===============================
  if(bid < 4){
    // o-WGs: redundant aw (13 pinned packed attn rows/wave) + o slice of 256.
    const int oi = bid*256 + tid;
    PChunk wa13[13];
    int srow[13];
    #pragma unroll
    for(int i=0;i<13;i++){
      int s = wave + 4*i; int sc = (s<LSEQ)? s : 0;
      wa13[i] = load_pchunk(A.attn_W + (size_t)sc*2*HDIM + HDIM, lane);
      pinp(wa13[i]);
      srow[i] = s;
    }
    unsigned mp[25];
    #pragma unroll
    for(int k=0;k<25;k++){
      mp[k] = pack2(A.MT[(2*k)*HDIM+oi], A.MT[(2*k+1)*HDIM+oi]);
      pin32(mp[k]);
    }
    for(int t=0;t<LSEQ;++t){
      const unsigned tg = (unsigned)(t&31);
      float ae[13];
      #pragma unroll
      for(int i=0;i<13;i++)
        ae[i] = (srow[i]<LSEQ)? A.attn_e[t*LSEQ+srow[i]] : 0.f;
      float pcv = A.pre_comb[t*HDIM+oi];
      stage_tag_p<1>(ldsp_h, A.hbD + (t%3)*HDIM, tid, tg);
      __syncthreads();
      h2 hp[8]; read8p(ldsp_h, hp, lane);
      float pl[13];
      #pragma unroll
      for(int i=0;i<13;i++) pl[i]=pdot(wa13[i],hp);
      wred_batch<13>(pl);
      if(lane==0){
        #pragma unroll
        for(int i=0;i<13;i++) if(srow[i]<LSEQ) smL[srow[i]]=pl[i]+ae[i];
      }
      __syncthreads();
      if(wave==0){
        float l = (lane<LSEQ)? smL[lane] : -1e30f;
        float m = wred_max(l);
        float pe = (lane<LSEQ)? expf(l-m) : 0.f;
        float ss = wred_sum(pe);
        if(lane<LSEQ) smA[lane] = pe/ss;
      }
      __syncthreads();
      if(tid<25) awpL[tid] = (h2){(_Float16)smA[2*tid],(_Float16)smA[2*tid+1]};
      __syncthreads();
      float acc = pcv;
      #pragma unroll
      for(int k=0;k<25;k++) acc = FDOT2(as_h2(mp[k]), awpL[k], acc);
      st_tag(&A.obD[(t&1)*HDIM+oi], fmaxf(acc,0.f), tg);
      __syncthreads();
    }
  } else if(bid == 4){
    // collect tagged logits, double log_softmax, out + loss
    float loss = 0.f;
    for(int t=0;t<LSEQ;++t){
      if(tid<32){
        const float* pp = A.logits + (t&1)*TDIM + 4*tid;
        const unsigned tg = (unsigned)(t&31);
        f32x4 v;
        for(;;){
          v = coh_load4(pp);
          unsigned m = ((__float_as_uint(v.x)&31u)^tg) | ((__float_as_uint(v.y)&31u)^tg)
                     | ((__float_as_uint(v.z)&31u)^tg) | ((__float_as_uint(v.w)&31u)^tg);
          if(m==0u) break;
          __builtin_amdgcn_s_sleep(2);
        }
        smL[4*tid]=v.x; smL[4*tid+1]=v.y; smL[4*tid+2]=v.z; smL[4*tid+3]=v.w;
      }
      __syncthreads();
      if(tid==0) stf(A.ctrV, (unsigned)(t+1));   // epoch t logits consumed
      if(wave==0){
        float l0=smL[lane], l1=smL[lane+64];
        float m  = wred_max(fmaxf(l0,l1));
        float pe = expf(l0-m)+expf(l1-m);
        float s1 = wred_sum(pe);
        float lse = m + logf(s1);
        float lp0 = l0-lse, lp1 = l1-lse;
        float m2  = wred_max(fmaxf(lp0,lp1));
        float p2  = expf(lp0-m2)+expf(lp1-m2);
        float s2  = wred_sum(p2);
        float lse2 = m2 + logf(s2);
        A.out[t*TDIM + lane]      = lp0;
        A.out[t*TDIM + 64 + lane] = lp1;
        int tg2 = A.tag_ids[t];
        float c = ((lane==tg2)?(lse2-lp0):0.f) + ((lane+64==tg2)?(lse2-lp1):0.f);
        c = wred_sum(c);
        if(tg2 != 0) loss += c;
      }
      __syncthreads();
    }
    if(tid==0) A.out[LSEQ*TDIM] = loss;
  } else if(is_prod){
    // producers: pinned packed wh + wi; stage h -> gh -> stage o -> gi -> h'
    PChunk whp[6], wip[6];
    #pragma unroll
    for(int i=0;i<6;i++){
      int r = wave + 4*i;
      int le=r/3, g=r-3*le, row=g*HDIM+base+le;
      whp[i] = load_pchunk(A.dec_Whh + (size_t)row*HDIM, lane);
      pinp(whp[i]);
      wip[i] = load_pchunk(A.dec_Wih + (size_t)row*HDIM, lane);
      pinp(wip[i]);
    }
    float dh0=A.dec_bhh[j8], dh1=A.dec_bhh[HDIM+j8], dh2=A.dec_bhh[2*HDIM+j8];
    float di0=A.dec_bih[j8], di1=A.dec_bih[HDIM+j8], di2=A.dec_bih[2*HDIM+j8];
    for(int t=0;t<LSEQ;++t){
      const unsigned tg = (unsigned)(t&31);
      stage_tag_p<1>(ldsp_h, A.hbD + (t%3)*HDIM, tid, tg);
      __syncthreads();
      h2 hp[8]; read8p(ldsp_h, hp, lane);
      float ph[6];
      #pragma unroll
      for(int i=0;i<6;i++) ph[i]=pdot(whp[i],hp);
      wred_batch<6>(ph);
      if(lane==0){
        #pragma unroll
        for(int i=0;i<6;i++) smr[wave+4*i]=ph[i];
      }
      // gate: out-proj WGs must have staged epoch t-2 before we clobber hbD
      if(wave==0 && t>=3){
        const unsigned tgt = 16u*(unsigned)(t-2);
        for(;;){
          unsigned v = (lane==0)? ldu(A.ctrO) : tgt;
          if(__all((int)(v>=tgt))) break;
          __builtin_amdgcn_s_sleep(2);
        }
      }
      stage_tag_p<1>(ldsp_o, A.obD + (t&1)*HDIM, tid, tg);
      __syncthreads();
      h2 op[8]; read8p(ldsp_o, op, lane);
      float po[6];
      #pragma unroll
      for(int i=0;i<6;i++) po[i]=pdot(wip[i],op);
      wred_batch<6>(po);
      if(lane==0){
        #pragma unroll
        for(int i=0;i<6;i++) smr[32+wave+4*i]=po[i];
      }
      __syncthreads();
      if(tid<8){
        int j = base+tid;
        float gr=smr[tid*3]+dh0,    gz=smr[tid*3+1]+dh1,    gn=smr[tid*3+2]+dh2;
        float ir=smr[32+tid*3]+di0, iz=smr[32+tid*3+1]+di1, inn=smr[32+tid*3+2]+di2;
        float hj = hread(ldsp_h, j);
        float r_=sigm(ir+gr), z_=sigm(iz+gz);
        float n_=tanhf(inn+r_*gn);
        float h2v=(1.f-z_)*n_+z_*hj;
        st_tag(&A.hbD[((t+1)%3)*HDIM+j], h2v, (unsigned)((t+1)&31));
      }
      __syncthreads();
    }
  } else {
    // out-proj: bids 134..149, 8 rows each, 2 rows/wave pinned packed
    const int ob = bid-134;
    PChunk wop[2];
    float bo[2];
    #pragma unroll
    for(int i=0;i<2;i++){
      int row = ob*8 + wave*2 + i;
      wop[i]=load_pchunk(A.out_W+(size_t)row*HDIM,lane);
      pinp(wop[i]);
      bo[i]=A.out_b[row];
    }
    for(int t=0;t<LSEQ;++t){
      const unsigned tg1 = (unsigned)((t+1)&31);
      stage_tag_p<2>(ldsp_h, A.hbD + ((t+1)%3)*HDIM, tid, tg1);
      __syncthreads();
      if(tid==0) addc0(A.ctrO);            // "I staged epoch t+1"
      h2 hp[8]; read8p(ldsp_h, hp, lane);
      float pt[2]={pdot(wop[0],hp),pdot(wop[1],hp)};
      wred_batch<2>(pt);
      if(wave==0 && t>=2){
        const unsigned tgt = (unsigned)(t-1);  // WG4 consumed epoch t-2
        for(;;){
          unsigned v = (lane==0)? ldu(A.ctrV) : tgt;
          if(__all((int)(v>=tgt))) break;
          __builtin_amdgcn_s_sleep(4);
        }
      }
      __syncthreads();
      if(lane==0){
        int row = ob*8 + wave*2;
        st_tag(&A.logits[(t&1)*TDIM + row],   pt[0]+bo[0], (unsigned)(t&31));
        st_tag(&A.logits[(t&1)*TDIM + row+1], pt[1]+bo[1], (unsigned)(t&31));
      }
      __syncthreads();
    }
  }
}

extern "C" void kernel_launch(void* const* d_in, const int* in_sizes, int n_in,
                              void* d_out, int out_size, void* d_ws, size_t ws_size,
                              hipStream_t stream){
  (void)in_sizes; (void)n_in; (void)out_size; (void)ws_size;
  KArgs A;
  A.input_ids = (const int*)d_in[0];
  A.tag_ids   = (const int*)d_in[1];
  A.word_embed= (const float*)d_in[2];
  A.enc_Wih   = (const float*)d_in[3];
  A.enc_Whh   = (const float*)d_in[4];
  A.enc_bih   = (const float*)d_in[5];
  A.enc_bhh   = (const float*)d_in[6];
  A.dec_embed = (const float*)d_in[7];
  A.attn_W    = (const float*)d_in[8];
  A.attn_b    = (const float*)d_in[9];
  A.comb_W    = (const float*)d_in[10];
  A.comb_b    = (const float*)d_in[11];
  A.dec_Wih   = (const float*)d_in[12];
  A.dec_Whh   = (const float*)d_in[13];
  A.dec_bih   = (const float*)d_in[14];
  A.dec_bhh   = (const float*)d_in[15];
  A.out_W     = (const float*)d_in[16];
  A.out_b     = (const float*)d_in[17];
  A.out       = (float*)d_out;

  unsigned* u = (unsigned*)d_ws;
  A.ctrP = u;          // 8 lines (stride 16u)
  A.ctrE = u + 128;
  A.ctrM = u + 256;
  A.ctrO = u + 384;    // single line
  A.ctrV = u + 448;    // single line
  float* f = (float*)d_ws + 1024;   // byte 4096, tagged region start
  A.hbE    = f; f += 2*HDIM;
  A.hbD    = f; f += 3*HDIM;
  A.obD    = f; f += 2*HDIM;
  A.logits = f; f += 2*TDIM;        // tagged region: 7424 floats
  A.GI       = f; f += LSEQ*G3;
  A.attn_e   = f; f += LSEQ*LSEQ + 14;
  A.pre_comb = f; f += LSEQ*HDIM;
  A.MT       = f; f += LSEQ*HDIM;
  A.enc_outs = f; f += LSEQ*HDIM;

  (void)hipMemsetAsync(d_ws, 0, 4096, stream);                        // counters
  (void)hipMemsetAsync((char*)d_ws + 4096, 0xFF, 7424*4, stream);     // tag bufs -> tag 31
  void* args[] = { &A };
  hipError_t err = hipLaunchCooperativeKernel((const void*)seq2seq_kernel,
                                              dim3(256), dim3(256), args, 0, stream);
  if(err != hipSuccess){
    // 256 WGs on 256 CUs are co-resident by capacity; cooperative API was
    // only belt-and-braces. Fall back to a normal launch.
    hipLaunchKernelGGL(seq2seq_kernel, dim3(256), dim3(256), 0, stream, A);
  }
}

// Round 13
// 463.892 us; speedup vs baseline: 1.4244x; 1.1019x over previous
//
#include <hip/hip_runtime.h>
#include <cstdint>

// Seq2Seq GRU enc/dec with attention, batch=1, L=50, H=1024, T=128 (fp32 in/out).
// Persistent cooperative kernel, 256 WGs x 256 threads.
// Sync: VALUE TAGS (low 5 mantissa bits = epoch); retry loads ARE the poll.
// Weights fp16-packed & pinned in VGPRs (v_dot2_f32_f16). Decoder = 2 hops:
// h -> o-WGs (redundant pinned attn + pinned M -> aw,o) -> producers -> h'.
// NEW (R13): no serial prologue. Producers compute their own GI into LDS and
// start the encoder immediately (no global barrier); the 128 spectator WGs
// compute attn_e + pre_comb DURING the encoder window.

#define HDIM 1024
#define LSEQ 50
#define TDIM 128
#define PB   6
#define NPROD 128
#define LSTRP 65

typedef float f32x4 __attribute__((ext_vector_type(4)));
typedef _Float16 h2 __attribute__((ext_vector_type(2)));

#if __has_builtin(__builtin_amdgcn_fdot2)
#define FDOT2(a,b,c) __builtin_amdgcn_fdot2((a),(b),(c),false)
#else
__device__ __forceinline__ float fdot2_sw(h2 a, h2 b, float c){
  return c + (float)a[0]*(float)b[0] + (float)a[1]*(float)b[1];
}
#define FDOT2(a,b,c) fdot2_sw((a),(b),(c))
#endif

struct KArgs {
  const int* input_ids; const int* tag_ids;
  const float* word_embed;
  const float* enc_Wih; const float* enc_Whh; const float* enc_bih; const float* enc_bhh;
  const float* dec_embed; const float* attn_W; const float* attn_b;
  const float* comb_W; const float* comb_b;
  const float* dec_Wih; const float* dec_Whh; const float* dec_bih; const float* dec_bhh;
  const float* out_W; const float* out_b;
  float* out;
  unsigned* ctrE; unsigned* ctrM; unsigned* ctrO; unsigned* ctrV;
  float* hbE;      // 2*1024 tagged
  float* hbD;      // 3*1024 tagged
  float* obD;      // 2*1024 tagged
  float* logits;   // 2*128  tagged
  float* attn_e;   // 50*50
  float* pre_comb; // 50*1024
  float* MT;       // 50*1024  (MT[s*H+i])
  float* enc_outs; // 50*1024
};

__device__ __forceinline__ void fence_vm(){
  asm volatile("s_waitcnt vmcnt(0)" ::: "memory");
}
__device__ __forceinline__ void st_coh(float* p, float v){
  __hip_atomic_store(p, v, __ATOMIC_RELAXED, __HIP_MEMORY_SCOPE_AGENT);
}
__device__ __forceinline__ void st_tag(float* p, float v, unsigned tag){
  unsigned b = (__float_as_uint(v) & ~31u) | tag;
  st_coh(p, __uint_as_float(b));
}
__device__ __forceinline__ void stf(unsigned* p, unsigned v){
  __hip_atomic_store(p, v, __ATOMIC_RELAXED, __HIP_MEMORY_SCOPE_AGENT);
}
__device__ __forceinline__ unsigned ldu(const unsigned* p){
  return __hip_atomic_load(p, __ATOMIC_RELAXED, __HIP_MEMORY_SCOPE_AGENT);
}
__device__ __forceinline__ void addc(unsigned* base, int bid){
  __hip_atomic_fetch_add(base + (bid&7)*16, 1u, __ATOMIC_RELAXED, __HIP_MEMORY_SCOPE_AGENT);
}
__device__ __forceinline__ void addc0(unsigned* base){
  __hip_atomic_fetch_add(base, 1u, __ATOMIC_RELAXED, __HIP_MEMORY_SCOPE_AGENT);
}
__device__ __forceinline__ f32x4 coh_load4(const float* p){
  f32x4 v;
  asm volatile("global_load_dwordx4 %0, %1, off sc0 sc1\n\ts_waitcnt vmcnt(0)"
               : "=v"(v) : "v"(p) : "memory");
  return v;
}

template<int N>
__device__ __forceinline__ void wred_batch(float* v){
  #pragma unroll
  for(int o=32;o>0;o>>=1){
    #pragma unroll
    for(int i=0;i<N;i++) v[i] += __shfl_xor(v[i],o,64);
  }
}
__device__ __forceinline__ float wred_sum(float v){
  #pragma unroll
  for(int o=32;o>0;o>>=1) v += __shfl_xor(v,o,64);
  return v;
}
__device__ __forceinline__ float wred_max(float v){
  #pragma unroll
  for(int o=32;o>0;o>>=1) v = fmaxf(v,__shfl_xor(v,o,64));
  return v;
}

// ---- fp32 chunk machinery (MT only) ----
struct Chunk { f32x4 a,b,c,d; };
__device__ __forceinline__ Chunk load_chunk(const float* __restrict__ row, int lane){
  const f32x4* p = reinterpret_cast<const f32x4*>(row) + lane*4;
  Chunk w; w.a=p[0]; w.b=p[1]; w.c=p[2]; w.d=p[3]; return w;
}
__device__ __forceinline__ float chunk_dot(const Chunk& w, const float* hc){
  return w.a.x*hc[0]+w.a.y*hc[1]+w.a.z*hc[2]+w.a.w*hc[3]
       + w.b.x*hc[4]+w.b.y*hc[5]+w.b.z*hc[6]+w.b.w*hc[7]
       + w.c.x*hc[8]+w.c.y*hc[9]+w.c.z*hc[10]+w.c.w*hc[11]
       + w.d.x*hc[12]+w.d.y*hc[13]+w.d.z*hc[14]+w.d.w*hc[15];
}
__device__ __forceinline__ void load_vec16(const float* __restrict__ v, float* hc, int lane){
  const f32x4* p = reinterpret_cast<const f32x4*>(v) + lane*4;
  f32x4 x0=p[0],x1=p[1],x2=p[2],x3=p[3];
  hc[0]=x0.x; hc[1]=x0.y; hc[2]=x0.z; hc[3]=x0.w;
  hc[4]=x1.x; hc[5]=x1.y; hc[6]=x1.z; hc[7]=x1.w;
  hc[8]=x2.x; hc[9]=x2.y; hc[10]=x2.z; hc[11]=x2.w;
  hc[12]=x3.x; hc[13]=x3.y; hc[14]=x3.z; hc[15]=x3.w;
}

// ---- fp16-packed row chunk: 16 weights as 8 packed pairs (8 VGPRs) ----
struct PChunk { unsigned m[8]; };
__device__ __forceinline__ h2 as_h2(unsigned u){ return __builtin_bit_cast(h2, u); }
__device__ __forceinline__ unsigned as_u(h2 h){ return __builtin_bit_cast(unsigned, h); }
__device__ __forceinline__ unsigned pack2(float a, float b){
  return as_u((h2){(_Float16)a, (_Float16)b});
}
__device__ __forceinline__ PChunk load_pchunk(const float* __restrict__ row, int lane){
  const f32x4* p = reinterpret_cast<const f32x4*>(row) + lane*4;
  f32x4 a=p[0],b=p[1],c=p[2],d=p[3];
  PChunk w;
  w.m[0]=pack2(a.x,a.y); w.m[1]=pack2(a.z,a.w);
  w.m[2]=pack2(b.x,b.y); w.m[3]=pack2(b.z,b.w);
  w.m[4]=pack2(c.x,c.y); w.m[5]=pack2(c.z,c.w);
  w.m[6]=pack2(d.x,d.y); w.m[7]=pack2(d.z,d.w);
  return w;
}
__device__ __forceinline__ void pinp(PChunk& c){
  asm volatile("" : "+v"(c.m[0]),"+v"(c.m[1]),"+v"(c.m[2]),"+v"(c.m[3]),
                    "+v"(c.m[4]),"+v"(c.m[5]),"+v"(c.m[6]),"+v"(c.m[7]));
}
__device__ __forceinline__ void pin32(unsigned& x){ asm volatile("" : "+v"(x)); }
__device__ __forceinline__ float pdot(const PChunk& w, const h2* hp){
  float acc = 0.f;
  #pragma unroll
  for(int k=0;k<8;k++) acc = FDOT2(as_h2(w.m[k]), hp[k], acc);
  return acc;
}
__device__ __forceinline__ float sigm(float x){ return 1.f/(1.f+expf(-x)); }
__device__ __forceinline__ void pack16(const float* ec, h2* ep){
  #pragma unroll
  for(int k=0;k<8;k++) ep[k]=(h2){(_Float16)ec[2*k],(_Float16)ec[2*k+1]};
}

// retry-stage 1024 tagged fp32 -> packed fp16 LDS. Element j lives in pair
// pj=j>>1 at ldsp[(pj&7)*LSTRP + (pj>>3)]. Retry until all 4 tags match.
template<int SLP>
__device__ __forceinline__ void stage_tag_p(h2* ldsp, const float* g, int tid, unsigned tag){
  const float* p = g + 4*tid;
  f32x4 v;
  for(;;){
    v = coh_load4(p);
    unsigned m = ((__float_as_uint(v.x)&31u)^tag) | ((__float_as_uint(v.y)&31u)^tag)
               | ((__float_as_uint(v.z)&31u)^tag) | ((__float_as_uint(v.w)&31u)^tag);
    if(m==0u) break;
    if(SLP) __builtin_amdgcn_s_sleep(SLP);
  }
  int q = tid>>2, m0 = (tid&3)*2;
  ldsp[m0*LSTRP+q]     = (h2){(_Float16)v.x,(_Float16)v.y};
  ldsp[(m0+1)*LSTRP+q] = (h2){(_Float16)v.z,(_Float16)v.w};
}
__device__ __forceinline__ void read8p(const h2* ldsp, h2* hp, int lane){
  #pragma unroll
  for(int k=0;k<8;k++) hp[k]=ldsp[k*LSTRP+lane];
}
__device__ __forceinline__ float hread(const h2* ldsp, int j){
  int pj = j>>1;
  h2 v = ldsp[(pj&7)*LSTRP + (pj>>3)];
  return (float)v[j&1];
}

__device__ __forceinline__ void wait8(const unsigned* base, unsigned n, int lane){
  const unsigned* p = base + lane*16;
  for(;;){
    unsigned v = (lane<8)? ldu(p) : 0xFFFFFFFFu;
    if(__all((int)(v>=n))) return;
    __builtin_amdgcn_s_sleep(8);
  }
}

__global__ __launch_bounds__(256,1) void seq2seq_kernel(KArgs A){
  const int bid = blockIdx.x, tid = threadIdx.x;
  const int wave = tid>>6, lane = tid&63;
  __shared__ h2 ldsp_h[8*LSTRP+8];
  __shared__ h2 ldsp_o[8*LSTRP+8];
  __shared__ h2 awpL[32];
  __shared__ float smr[64];
  __shared__ float smL[TDIM];
  __shared__ float smA[64];
  __shared__ float giL[LSEQ*24];   // producer-local GI (bih folded)

  const int gv = bid*4 + wave;   // 0..1023

  // producer geometry: bids 6..133 own 8 h-elements each
  const int p = bid - PB;
  const bool is_prod = (p>=0 && p<NPROD);
  const int base = is_prod ? p*8 : 0;
  const int j8 = base + (tid&7);

  // ================= phase A (no global barrier) ============================
  if(is_prod){
    // ---- GI-local: own 24 rows x 50 steps -> LDS (then encoder at once) ----
    {
      PChunk wgi[6]; float bgi[6];
      #pragma unroll
      for(int i=0;i<6;i++){
        int r = wave + 4*i;               // r = 3*le + g
        int le=r/3, g=r-3*le, grow=g*HDIM+base+le;
        wgi[i] = load_pchunk(A.enc_Wih + (size_t)grow*HDIM, lane);
        pinp(wgi[i]);
        bgi[i] = A.enc_bih[grow];
      }
      for(int te=0;te<LSEQ;++te){
        int tok = A.input_ids[te];
        float ec[16]; load_vec16(A.word_embed + (size_t)tok*HDIM, ec, lane);
        h2 ep[8]; pack16(ec, ep);
        float d[6];
        #pragma unroll
        for(int i=0;i<6;i++) d[i]=pdot(wgi[i],ep);
        wred_batch<6>(d);
        if(lane==0){
          #pragma unroll
          for(int i=0;i<6;i++) giL[te*24 + wave+4*i] = d[i]+bgi[i];
        }
      }
      __syncthreads();
    }
    // ---- encoder: 50 sequential GRU steps ----
    PChunk wep[6];
    #pragma unroll
    for(int i=0;i<6;i++){
      int r = wave + 4*i;
      int le=r/3, g=r-3*le, row=g*HDIM+base+le;
      wep[i] = load_pchunk(A.enc_Whh + (size_t)row*HDIM, lane);
      pinp(wep[i]);
    }
    float bh0=A.enc_bhh[j8], bh1=A.enc_bhh[HDIM+j8], bh2=A.enc_bhh[2*HDIM+j8];
    for(int te=0;te<LSEQ;++te){
      h2 hp[8];
      if(te>0){
        stage_tag_p<1>(ldsp_h, A.hbE + ((te-1)&1)*HDIM, tid, (unsigned)(te&31));
        __syncthreads();
        read8p(ldsp_h, hp, lane);
      } else {
        #pragma unroll
        for(int k=0;k<8;k++) hp[k]=(h2){(_Float16)0.f,(_Float16)0.f};
      }
      float part[6];
      #pragma unroll
      for(int i=0;i<6;i++) part[i]=pdot(wep[i],hp);
      wred_batch<6>(part);
      if(lane==0){
        #pragma unroll
        for(int i=0;i<6;i++) smr[wave+4*i]=part[i];
      }
      __syncthreads();
      if(tid<8){
        int j = base+tid;
        float gr=smr[tid*3]+bh0, gz=smr[tid*3+1]+bh1, gn=smr[tid*3+2]+bh2;
        float gi0=giL[te*24+3*tid], gi1=giL[te*24+3*tid+1], gi2=giL[te*24+3*tid+2];
        float hj = (te>0)? hread(ldsp_h, j) : 0.f;
        float r_=sigm(gi0+gr), z_=sigm(gi1+gz);
        float n_=tanhf(gi2+r_*gn);
        float h2v=(1.f-z_)*n_+z_*hj;
        st_tag(&A.hbE[(te&1)*HDIM+j], h2v, (unsigned)((te+1)&31));
        st_coh(&A.enc_outs[te*HDIM+j], h2v);
        if(te==LSEQ-1) st_tag(&A.hbD[j], h2v, 0u);
      }
      __syncthreads();
    }
    fence_vm();
    __syncthreads();
    if(tid==0) addc(A.ctrE, bid);
  } else {
    // ---- spectators (exactly 128): attn_e + pre_comb during the encoder ----
    const int q = (bid<6)? bid : bid-128;   // 0..127
    PChunk wpc[2]; float bpc[2]; int ri[2];
    #pragma unroll
    for(int k=0;k<2;k++){
      ri[k] = q*8 + wave*2 + k;
      wpc[k] = load_pchunk(A.comb_W + (size_t)ri[k]*2*HDIM, lane);
      pinp(wpc[k]);
      bpc[k] = A.comb_b[ri[k]];
    }
    for(int t=0;t<LSEQ;++t){
      int tok = (t==0)?1:A.tag_ids[t-1];
      float ec[16]; load_vec16(A.dec_embed + (size_t)tok*HDIM, ec, lane);
      h2 ep[8]; pack16(ec, ep);
      float d[2] = {pdot(wpc[0],ep), pdot(wpc[1],ep)};
      wred_batch<2>(d);
      if(lane==0){
        st_coh(&A.pre_comb[t*HDIM+ri[0]], d[0]+bpc[0]);
        st_coh(&A.pre_comb[t*HDIM+ri[1]], d[1]+bpc[1]);
      }
    }
    if(q < LSEQ){
      PChunk wae = load_pchunk(A.attn_W + (size_t)q*2*HDIM, lane);
      float bae = A.attn_b[q];
      const int t0 = wave*13, tc = (wave<3)?13:11;
      for(int u=0;u<tc;++u){
        int t = t0+u;
        int tok = (t==0)?1:A.tag_ids[t-1];
        float ec[16]; load_vec16(A.dec_embed + (size_t)tok*HDIM, ec, lane);
        h2 ep[8]; pack16(ec, ep);
        float d = wred_sum(pdot(wae,ep));
        if(lane==0) st_coh(&A.attn_e[t*LSEQ+q], d+bae);
      }
    }
    fence_vm();
    __syncthreads();
  }

  // ================= MT = comb_W[:,H:] @ enc_outs^T (all WGs) ===============
  if(wave==0) wait8(A.ctrE, 16u, lane);   // 128 producers -> 16 per class
  __syncthreads();
  {
    Chunk wm = load_chunk(A.comb_W + (size_t)gv*2*HDIM + HDIM, lane);
    for(int sg=0;sg<10;++sg){
      float pt[5];
      #pragma unroll
      for(int j=0;j<5;j++){
        float ec[16]; load_vec16(A.enc_outs + (sg*5+j)*HDIM, ec, lane);
        pt[j]=chunk_dot(wm,ec);
      }
      wred_batch<5>(pt);
      if(lane==0){
        #pragma unroll
        for(int j=0;j<5;j++) st_coh(&A.MT[(sg*5+j)*HDIM+gv], pt[j]);
      }
    }
  }
  fence_vm();
  __syncthreads();
  if(tid==0) addc(A.ctrM, bid);
  {
    const bool keep = is_prod || bid<5 || (bid>=134 && bid<150);
    if(!keep) return;                      // spectators done
  }
  if(wave==0) wait8(A.ctrM, 32u, lane);
  __syncthreads();

  // ================= decoder: 50 steps, 2 hops ===============================
  if(bid < 4){
    // o-WGs: redundant aw (13 pinned packed attn rows/wave) + o slice of 256.
    const int oi = bid*256 + tid;
    PChunk wa13[13];
    int srow[13];
    #pragma unroll
    for(int i=0;i<13;i++){
      int s = wave + 4*i; int sc = (s<LSEQ)? s : 0;
      wa13[i] = load_pchunk(A.attn_W + (size_t)sc*2*HDIM + HDIM, lane);
      pinp(wa13[i]);
      srow[i] = s;
    }
    unsigned mp[25];
    #pragma unroll
    for(int k=0;k<25;k++){
      mp[k] = pack2(A.MT[(2*k)*HDIM+oi], A.MT[(2*k+1)*HDIM+oi]);
      pin32(mp[k]);
    }
    for(int t=0;t<LSEQ;++t){
      const unsigned tg = (unsigned)(t&31);
      float ae[13];
      #pragma unroll
      for(int i=0;i<13;i++)
        ae[i] = (srow[i]<LSEQ)? A.attn_e[t*LSEQ+srow[i]] : 0.f;
      float pcv = A.pre_comb[t*HDIM+oi];
      stage_tag_p<1>(ldsp_h, A.hbD + (t%3)*HDIM, tid, tg);
      __syncthreads();
      h2 hp[8]; read8p(ldsp_h, hp, lane);
      float pl[13];
      #pragma unroll
      for(int i=0;i<13;i++) pl[i]=pdot(wa13[i],hp);
      wred_batch<13>(pl);
      if(lane==0){
        #pragma unroll
        for(int i=0;i<13;i++) if(srow[i]<LSEQ) smL[srow[i]]=pl[i]+ae[i];
      }
      __syncthreads();
      if(wave==0){
        float l = (lane<LSEQ)? smL[lane] : -1e30f;
        float m = wred_max(l);
        float pe = (lane<LSEQ)? expf(l-m) : 0.f;
        float ss = wred_sum(pe);
        if(lane<LSEQ) smA[lane] = pe/ss;
      }
      __syncthreads();
      if(tid<25) awpL[tid] = (h2){(_Float16)smA[2*tid],(_Float16)smA[2*tid+1]};
      __syncthreads();
      float acc = pcv;
      #pragma unroll
      for(int k=0;k<25;k++) acc = FDOT2(as_h2(mp[k]), awpL[k], acc);
      st_tag(&A.obD[(t&1)*HDIM+oi], fmaxf(acc,0.f), tg);
      __syncthreads();
    }
  } else if(bid == 4){
    // collect tagged logits, double log_softmax, out + loss
    float loss = 0.f;
    for(int t=0;t<LSEQ;++t){
      if(tid<32){
        const float* pp = A.logits + (t&1)*TDIM + 4*tid;
        const unsigned tg = (unsigned)(t&31);
        f32x4 v;
        for(;;){
          v = coh_load4(pp);
          unsigned m = ((__float_as_uint(v.x)&31u)^tg) | ((__float_as_uint(v.y)&31u)^tg)
                     | ((__float_as_uint(v.z)&31u)^tg) | ((__float_as_uint(v.w)&31u)^tg);
          if(m==0u) break;
          __builtin_amdgcn_s_sleep(2);
        }
        smL[4*tid]=v.x; smL[4*tid+1]=v.y; smL[4*tid+2]=v.z; smL[4*tid+3]=v.w;
      }
      __syncthreads();
      if(tid==0) stf(A.ctrV, (unsigned)(t+1));   // epoch t logits consumed
      if(wave==0){
        float l0=smL[lane], l1=smL[lane+64];
        float m  = wred_max(fmaxf(l0,l1));
        float pe = expf(l0-m)+expf(l1-m);
        float s1 = wred_sum(pe);
        float lse = m + logf(s1);
        float lp0 = l0-lse, lp1 = l1-lse;
        float m2  = wred_max(fmaxf(lp0,lp1));
        float p2  = expf(lp0-m2)+expf(lp1-m2);
        float s2  = wred_sum(p2);
        float lse2 = m2 + logf(s2);
        A.out[t*TDIM + lane]      = lp0;
        A.out[t*TDIM + 64 + lane] = lp1;
        int tg2 = A.tag_ids[t];
        float c = ((lane==tg2)?(lse2-lp0):0.f) + ((lane+64==tg2)?(lse2-lp1):0.f);
        c = wred_sum(c);
        if(tg2 != 0) loss += c;
      }
      __syncthreads();
    }
    if(tid==0) A.out[LSEQ*TDIM] = loss;
  } else if(is_prod){
    // producers: pinned packed wh + wi; stage h -> gh -> stage o -> gi -> h'
    PChunk whp[6], wip[6];
    #pragma unroll
    for(int i=0;i<6;i++){
      int r = wave + 4*i;
      int le=r/3, g=r-3*le, row=g*HDIM+base+le;
      whp[i] = load_pchunk(A.dec_Whh + (size_t)row*HDIM, lane);
      pinp(whp[i]);
      wip[i] = load_pchunk(A.dec_Wih + (size_t)row*HDIM, lane);
      pinp(wip[i]);
    }
    float dh0=A.dec_bhh[j8], dh1=A.dec_bhh[HDIM+j8], dh2=A.dec_bhh[2*HDIM+j8];
    float di0=A.dec_bih[j8], di1=A.dec_bih[HDIM+j8], di2=A.dec_bih[2*HDIM+j8];
    for(int t=0;t<LSEQ;++t){
      const unsigned tg = (unsigned)(t&31);
      stage_tag_p<1>(ldsp_h, A.hbD + (t%3)*HDIM, tid, tg);
      __syncthreads();
      h2 hp[8]; read8p(ldsp_h, hp, lane);
      float ph[6];
      #pragma unroll
      for(int i=0;i<6;i++) ph[i]=pdot(whp[i],hp);
      wred_batch<6>(ph);
      if(lane==0){
        #pragma unroll
        for(int i=0;i<6;i++) smr[wave+4*i]=ph[i];
      }
      // gate: out-proj WGs must have staged epoch t-2 before we clobber hbD
      if(wave==0 && t>=3){
        const unsigned tgt = 16u*(unsigned)(t-2);
        for(;;){
          unsigned v = (lane==0)? ldu(A.ctrO) : tgt;
          if(__all((int)(v>=tgt))) break;
          __builtin_amdgcn_s_sleep(2);
        }
      }
      stage_tag_p<1>(ldsp_o, A.obD + (t&1)*HDIM, tid, tg);
      __syncthreads();
      h2 op[8]; read8p(ldsp_o, op, lane);
      float po[6];
      #pragma unroll
      for(int i=0;i<6;i++) po[i]=pdot(wip[i],op);
      wred_batch<6>(po);
      if(lane==0){
        #pragma unroll
        for(int i=0;i<6;i++) smr[32+wave+4*i]=po[i];
      }
      __syncthreads();
      if(tid<8){
        int j = base+tid;
        float gr=smr[tid*3]+dh0,    gz=smr[tid*3+1]+dh1,    gn=smr[tid*3+2]+dh2;
        float ir=smr[32+tid*3]+di0, iz=smr[32+tid*3+1]+di1, inn=smr[32+tid*3+2]+di2;
        float hj = hread(ldsp_h, j);
        float r_=sigm(ir+gr), z_=sigm(iz+gz);
        float n_=tanhf(inn+r_*gn);
        float h2v=(1.f-z_)*n_+z_*hj;
        st_tag(&A.hbD[((t+1)%3)*HDIM+j], h2v, (unsigned)((t+1)&31));
      }
      __syncthreads();
    }
  } else {
    // out-proj: bids 134..149, 8 rows each, 2 rows/wave pinned packed
    const int ob = bid-134;
    PChunk wop[2];
    float bo[2];
    #pragma unroll
    for(int i=0;i<2;i++){
      int row = ob*8 + wave*2 + i;
      wop[i]=load_pchunk(A.out_W+(size_t)row*HDIM,lane);
      pinp(wop[i]);
      bo[i]=A.out_b[row];
    }
    for(int t=0;t<LSEQ;++t){
      const unsigned tg1 = (unsigned)((t+1)&31);
      stage_tag_p<2>(ldsp_h, A.hbD + ((t+1)%3)*HDIM, tid, tg1);
      __syncthreads();
      if(tid==0) addc0(A.ctrO);            // "I staged epoch t+1"
      h2 hp[8]; read8p(ldsp_h, hp, lane);
      float pt[2]={pdot(wop[0],hp),pdot(wop[1],hp)};
      wred_batch<2>(pt);
      if(wave==0 && t>=2){
        const unsigned tgt = (unsigned)(t-1);  // WG4 consumed epoch t-2
        for(;;){
          unsigned v = (lane==0)? ldu(A.ctrV) : tgt;
          if(__all((int)(v>=tgt))) break;
          __builtin_amdgcn_s_sleep(4);
        }
      }
      __syncthreads();
      if(lane==0){
        int row = ob*8 + wave*2;
        st_tag(&A.logits[(t&1)*TDIM + row],   pt[0]+bo[0], (unsigned)(t&31));
        st_tag(&A.logits[(t&1)*TDIM + row+1], pt[1]+bo[1], (unsigned)(t&31));
      }
      __syncthreads();
    }
  }
}

extern "C" void kernel_launch(void* const* d_in, const int* in_sizes, int n_in,
                              void* d_out, int out_size, void* d_ws, size_t ws_size,
                              hipStream_t stream){
  (void)in_sizes; (void)n_in; (void)out_size; (void)ws_size;
  KArgs A;
  A.input_ids = (const int*)d_in[0];
  A.tag_ids   = (const int*)d_in[1];
  A.word_embed= (const float*)d_in[2];
  A.enc_Wih   = (const float*)d_in[3];
  A.enc_Whh   = (const float*)d_in[4];
  A.enc_bih   = (const float*)d_in[5];
  A.enc_bhh   = (const float*)d_in[6];
  A.dec_embed = (const float*)d_in[7];
  A.attn_W    = (const float*)d_in[8];
  A.attn_b    = (const float*)d_in[9];
  A.comb_W    = (const float*)d_in[10];
  A.comb_b    = (const float*)d_in[11];
  A.dec_Wih   = (const float*)d_in[12];
  A.dec_Whh   = (const float*)d_in[13];
  A.dec_bih   = (const float*)d_in[14];
  A.dec_bhh   = (const float*)d_in[15];
  A.out_W     = (const float*)d_in[16];
  A.out_b     = (const float*)d_in[17];
  A.out       = (float*)d_out;

  unsigned* u = (unsigned*)d_ws;
  A.ctrE = u;          // 8 lines (stride 16u)
  A.ctrM = u + 128;
  A.ctrO = u + 256;    // single line
  A.ctrV = u + 320;    // single line
  float* f = (float*)d_ws + 1024;   // byte 4096, tagged region start
  A.hbE    = f; f += 2*HDIM;
  A.hbD    = f; f += 3*HDIM;
  A.obD    = f; f += 2*HDIM;
  A.logits = f; f += 2*TDIM;        // tagged region: 7424 floats
  A.attn_e   = f; f += LSEQ*LSEQ + 14;
  A.pre_comb = f; f += LSEQ*HDIM;
  A.MT       = f; f += LSEQ*HDIM;
  A.enc_outs = f; f += LSEQ*HDIM;

  (void)hipMemsetAsync(d_ws, 0, 4096, stream);                        // counters
  (void)hipMemsetAsync((char*)d_ws + 4096, 0xFF, 7424*4, stream);     // tag bufs -> tag 31
  void* args[] = { &A };
  hipError_t err = hipLaunchCooperativeKernel((const void*)seq2seq_kernel,
                                              dim3(256), dim3(256), args, 0, stream);
  if(err != hipSuccess){
    // 256 WGs on 256 CUs are co-resident by capacity; cooperative API was
    // only belt-and-braces. Fall back to a normal launch.
    hipLaunchKernelGGL(seq2seq_kernel, dim3(256), dim3(256), 0, stream, A);
  }
}

// Round 14
// 458.838 us; speedup vs baseline: 1.4401x; 1.0110x over previous
//
#include <hip/hip_runtime.h>
#include <cstdint>

// Seq2Seq GRU enc/dec with attention, batch=1, L=50, H=1024, T=128 (fp32 in/out).
// Persistent cooperative kernel, 256 WGs x 256 threads.
// Sync: VALUE TAGS (low 5 mantissa bits = epoch); retry loads ARE the poll.
// Weights fp16-packed & pinned in VGPRs (v_dot2_f32_f16). Decoder = 2 hops.
// R13: GI local to producers; spectators do attn_e/pre_comb during encoder.
// R14: MT pipelined onto spectators DURING the encoder (enc_outs is per-element
// tagged, write-once); all inter-phase global barriers removed — only o-WGs
// wait on one "spectators done" counter before loading their MT columns.

#define HDIM 1024
#define LSEQ 50
#define TDIM 128
#define PB   6
#define NPROD 128
#define LSTRP 65

typedef float f32x4 __attribute__((ext_vector_type(4)));
typedef _Float16 h2 __attribute__((ext_vector_type(2)));

#if __has_builtin(__builtin_amdgcn_fdot2)
#define FDOT2(a,b,c) __builtin_amdgcn_fdot2((a),(b),(c),false)
#else
__device__ __forceinline__ float fdot2_sw(h2 a, h2 b, float c){
  return c + (float)a[0]*(float)b[0] + (float)a[1]*(float)b[1];
}
#define FDOT2(a,b,c) fdot2_sw((a),(b),(c))
#endif

struct KArgs {
  const int* input_ids; const int* tag_ids;
  const float* word_embed;
  const float* enc_Wih; const float* enc_Whh; const float* enc_bih; const float* enc_bhh;
  const float* dec_embed; const float* attn_W; const float* attn_b;
  const float* comb_W; const float* comb_b;
  const float* dec_Wih; const float* dec_Whh; const float* dec_bih; const float* dec_bhh;
  const float* out_W; const float* out_b;
  float* out;
  unsigned* ctrM; unsigned* ctrO; unsigned* ctrV;
  float* hbE;      // 2*1024 tagged
  float* hbD;      // 3*1024 tagged
  float* obD;      // 2*1024 tagged
  float* logits;   // 2*128  tagged
  float* enc_outs; // 50*1024 tagged (write-once, tag = te%31)
  float* attn_e;   // 50*50
  float* pre_comb; // 50*1024
  float* MT;       // 50*1024  (MT[s*H+i])
};

__device__ __forceinline__ void fence_vm(){
  asm volatile("s_waitcnt vmcnt(0)" ::: "memory");
}
__device__ __forceinline__ void st_coh(float* p, float v){
  __hip_atomic_store(p, v, __ATOMIC_RELAXED, __HIP_MEMORY_SCOPE_AGENT);
}
__device__ __forceinline__ void st_tag(float* p, float v, unsigned tag){
  unsigned b = (__float_as_uint(v) & ~31u) | tag;
  st_coh(p, __uint_as_float(b));
}
__device__ __forceinline__ void stf(unsigned* p, unsigned v){
  __hip_atomic_store(p, v, __ATOMIC_RELAXED, __HIP_MEMORY_SCOPE_AGENT);
}
__device__ __forceinline__ unsigned ldu(const unsigned* p){
  return __hip_atomic_load(p, __ATOMIC_RELAXED, __HIP_MEMORY_SCOPE_AGENT);
}
__device__ __forceinline__ void addc0(unsigned* base){
  __hip_atomic_fetch_add(base, 1u, __ATOMIC_RELAXED, __HIP_MEMORY_SCOPE_AGENT);
}
__device__ __forceinline__ f32x4 coh_load4(const float* p){
  f32x4 v;
  asm volatile("global_load_dwordx4 %0, %1, off sc0 sc1\n\ts_waitcnt vmcnt(0)"
               : "=v"(v) : "v"(p) : "memory");
  return v;
}

template<int N>
__device__ __forceinline__ void wred_batch(float* v){
  #pragma unroll
  for(int o=32;o>0;o>>=1){
    #pragma unroll
    for(int i=0;i<N;i++) v[i] += __shfl_xor(v[i],o,64);
  }
}
__device__ __forceinline__ float wred_sum(float v){
  #pragma unroll
  for(int o=32;o>0;o>>=1) v += __shfl_xor(v,o,64);
  return v;
}
__device__ __forceinline__ float wred_max(float v){
  #pragma unroll
  for(int o=32;o>0;o>>=1) v = fmaxf(v,__shfl_xor(v,o,64));
  return v;
}

// ---- fp32 vec16 load (word_embed / dec_embed, untagged) ----
__device__ __forceinline__ void load_vec16(const float* __restrict__ v, float* hc, int lane){
  const f32x4* p = reinterpret_cast<const f32x4*>(v) + lane*4;
  f32x4 x0=p[0],x1=p[1],x2=p[2],x3=p[3];
  hc[0]=x0.x; hc[1]=x0.y; hc[2]=x0.z; hc[3]=x0.w;
  hc[4]=x1.x; hc[5]=x1.y; hc[6]=x1.z; hc[7]=x1.w;
  hc[8]=x2.x; hc[9]=x2.y; hc[10]=x2.z; hc[11]=x2.w;
  hc[12]=x3.x; hc[13]=x3.y; hc[14]=x3.z; hc[15]=x3.w;
}

// ---- fp16-packed row chunk: 16 weights as 8 packed pairs (8 VGPRs) ----
struct PChunk { unsigned m[8]; };
__device__ __forceinline__ h2 as_h2(unsigned u){ return __builtin_bit_cast(h2, u); }
__device__ __forceinline__ unsigned as_u(h2 h){ return __builtin_bit_cast(unsigned, h); }
__device__ __forceinline__ unsigned pack2(float a, float b){
  return as_u((h2){(_Float16)a, (_Float16)b});
}
__device__ __forceinline__ PChunk load_pchunk(const float* __restrict__ row, int lane){
  const f32x4* p = reinterpret_cast<const f32x4*>(row) + lane*4;
  f32x4 a=p[0],b=p[1],c=p[2],d=p[3];
  PChunk w;
  w.m[0]=pack2(a.x,a.y); w.m[1]=pack2(a.z,a.w);
  w.m[2]=pack2(b.x,b.y); w.m[3]=pack2(b.z,b.w);
  w.m[4]=pack2(c.x,c.y); w.m[5]=pack2(c.z,c.w);
  w.m[6]=pack2(d.x,d.y); w.m[7]=pack2(d.z,d.w);
  return w;
}
__device__ __forceinline__ void pinp(PChunk& c){
  asm volatile("" : "+v"(c.m[0]),"+v"(c.m[1]),"+v"(c.m[2]),"+v"(c.m[3]),
                    "+v"(c.m[4]),"+v"(c.m[5]),"+v"(c.m[6]),"+v"(c.m[7]));
}
__device__ __forceinline__ void pin32(unsigned& x){ asm volatile("" : "+v"(x)); }
__device__ __forceinline__ float pdot(const PChunk& w, const h2* hp){
  float acc = 0.f;
  #pragma unroll
  for(int k=0;k<8;k++) acc = FDOT2(as_h2(w.m[k]), hp[k], acc);
  return acc;
}
__device__ __forceinline__ float sigm(float x){ return 1.f/(1.f+expf(-x)); }
__device__ __forceinline__ void pack16(const float* ec, h2* ep){
  #pragma unroll
  for(int k=0;k<8;k++) ep[k]=(h2){(_Float16)ec[2*k],(_Float16)ec[2*k+1]};
}

// retry-stage 1024 tagged fp32 -> packed fp16 LDS. Element j lives in pair
// pj=j>>1 at ldsp[(pj&7)*LSTRP + (pj>>3)]. Retry until all 4 tags match.
template<int SLP>
__device__ __forceinline__ void stage_tag_p(h2* ldsp, const float* g, int tid, unsigned tag){
  const float* p = g + 4*tid;
  f32x4 v;
  for(;;){
    v = coh_load4(p);
    unsigned m = ((__float_as_uint(v.x)&31u)^tag) | ((__float_as_uint(v.y)&31u)^tag)
               | ((__float_as_uint(v.z)&31u)^tag) | ((__float_as_uint(v.w)&31u)^tag);
    if(m==0u) break;
    if(SLP) __builtin_amdgcn_s_sleep(SLP);
  }
  int q = tid>>2, m0 = (tid&3)*2;
  ldsp[m0*LSTRP+q]     = (h2){(_Float16)v.x,(_Float16)v.y};
  ldsp[(m0+1)*LSTRP+q] = (h2){(_Float16)v.z,(_Float16)v.w};
}
__device__ __forceinline__ void read8p(const h2* ldsp, h2* hp, int lane){
  #pragma unroll
  for(int k=0;k<8;k++) hp[k]=ldsp[k*LSTRP+lane];
}
__device__ __forceinline__ float hread(const h2* ldsp, int j){
  int pj = j>>1;
  h2 v = ldsp[(pj&7)*LSTRP + (pj>>3)];
  return (float)v[j&1];
}

// spectator MT-pipeline: cheap per-lane detect (two 4B tags), off critical path
__device__ __forceinline__ void wait2_enc(const float* g, unsigned tg, int lane){
  const float* p0 = g + lane*16 + 7;
  const float* p1 = g + lane*16 + 15;
  for(;;){
    float a,b;
    asm volatile("global_load_dword %0, %2, off sc0 sc1\n\t"
                 "global_load_dword %1, %3, off sc0 sc1\n\t"
                 "s_waitcnt vmcnt(0)"
                 : "=v"(a), "=v"(b) : "v"(p0), "v"(p1) : "memory");
    unsigned m = ((__float_as_uint(a)&31u)^tg) | ((__float_as_uint(b)&31u)^tg);
    if(__all((int)(m==0u))) return;
    __builtin_amdgcn_s_sleep(4);
  }
}
// bulk 16-float tagged load -> packed (verify-retry; normally passes 1st try)
__device__ __forceinline__ void load16_tag(const float* g, unsigned tg, int lane, h2* ep){
  const float* p = g + lane*16;
  for(;;){
    f32x4 a=coh_load4(p), b=coh_load4(p+4), c=coh_load4(p+8), d=coh_load4(p+12);
    unsigned m = ((__float_as_uint(a.x)&31u)^tg)|((__float_as_uint(a.y)&31u)^tg)
               | ((__float_as_uint(a.z)&31u)^tg)|((__float_as_uint(a.w)&31u)^tg)
               | ((__float_as_uint(b.x)&31u)^tg)|((__float_as_uint(b.y)&31u)^tg)
               | ((__float_as_uint(b.z)&31u)^tg)|((__float_as_uint(b.w)&31u)^tg)
               | ((__float_as_uint(c.x)&31u)^tg)|((__float_as_uint(c.y)&31u)^tg)
               | ((__float_as_uint(c.z)&31u)^tg)|((__float_as_uint(c.w)&31u)^tg)
               | ((__float_as_uint(d.x)&31u)^tg)|((__float_as_uint(d.y)&31u)^tg)
               | ((__float_as_uint(d.z)&31u)^tg)|((__float_as_uint(d.w)&31u)^tg);
    if(m==0u){
      ep[0]=(h2){(_Float16)a.x,(_Float16)a.y}; ep[1]=(h2){(_Float16)a.z,(_Float16)a.w};
      ep[2]=(h2){(_Float16)b.x,(_Float16)b.y}; ep[3]=(h2){(_Float16)b.z,(_Float16)b.w};
      ep[4]=(h2){(_Float16)c.x,(_Float16)c.y}; ep[5]=(h2){(_Float16)c.z,(_Float16)c.w};
      ep[6]=(h2){(_Float16)d.x,(_Float16)d.y}; ep[7]=(h2){(_Float16)d.z,(_Float16)d.w};
      return;
    }
    __builtin_amdgcn_s_sleep(2);
  }
}

__global__ __launch_bounds__(256,1) void seq2seq_kernel(KArgs A){
  const int bid = blockIdx.x, tid = threadIdx.x;
  const int wave = tid>>6, lane = tid&63;
  __shared__ h2 ldsp_h[8*LSTRP+8];
  __shared__ h2 ldsp_o[8*LSTRP+8];
  __shared__ h2 awpL[32];
  __shared__ float smr[64];
  __shared__ float smL[TDIM];
  __shared__ float smA[64];
  __shared__ float giL[LSEQ*24];   // producer-local GI (bih folded)

  // producer geometry: bids 6..133 own 8 h-elements each
  const int p = bid - PB;
  const bool is_prod = (p>=0 && p<NPROD);
  const int base = is_prod ? p*8 : 0;
  const int j8 = base + (tid&7);

  // ================= phase A (no global barrier anywhere) ===================
  if(is_prod){
    // ---- GI-local: own 24 rows x 50 steps -> LDS ----
    {
      PChunk wgi[6]; float bgi[6];
      #pragma unroll
      for(int i=0;i<6;i++){
        int r = wave + 4*i;               // r = 3*le + g
        int le=r/3, g=r-3*le, grow=g*HDIM+base+le;
        wgi[i] = load_pchunk(A.enc_Wih + (size_t)grow*HDIM, lane);
        pinp(wgi[i]);
        bgi[i] = A.enc_bih[grow];
      }
      for(int te=0;te<LSEQ;++te){
        int tok = A.input_ids[te];
        float ec[16]; load_vec16(A.word_embed + (size_t)tok*HDIM, ec, lane);
        h2 ep[8]; pack16(ec, ep);
        float d[6];
        #pragma unroll
        for(int i=0;i<6;i++) d[i]=pdot(wgi[i],ep);
        wred_batch<6>(d);
        if(lane==0){
          #pragma unroll
          for(int i=0;i<6;i++) giL[te*24 + wave+4*i] = d[i]+bgi[i];
        }
      }
      __syncthreads();
    }
    // ---- encoder: 50 sequential GRU steps ----
    PChunk wep[6];
    #pragma unroll
    for(int i=0;i<6;i++){
      int r = wave + 4*i;
      int le=r/3, g=r-3*le, row=g*HDIM+base+le;
      wep[i] = load_pchunk(A.enc_Whh + (size_t)row*HDIM, lane);
      pinp(wep[i]);
    }
    float bh0=A.enc_bhh[j8], bh1=A.enc_bhh[HDIM+j8], bh2=A.enc_bhh[2*HDIM+j8];
    for(int te=0;te<LSEQ;++te){
      h2 hp[8];
      if(te>0){
        stage_tag_p<1>(ldsp_h, A.hbE + ((te-1)&1)*HDIM, tid, (unsigned)(te&31));
        __syncthreads();
        read8p(ldsp_h, hp, lane);
      } else {
        #pragma unroll
        for(int k=0;k<8;k++) hp[k]=(h2){(_Float16)0.f,(_Float16)0.f};
      }
      float part[6];
      #pragma unroll
      for(int i=0;i<6;i++) part[i]=pdot(wep[i],hp);
      wred_batch<6>(part);
      if(lane==0){
        #pragma unroll
        for(int i=0;i<6;i++) smr[wave+4*i]=part[i];
      }
      __syncthreads();
      if(tid<8){
        int j = base+tid;
        float gr=smr[tid*3]+bh0, gz=smr[tid*3+1]+bh1, gn=smr[tid*3+2]+bh2;
        float gi0=giL[te*24+3*tid], gi1=giL[te*24+3*tid+1], gi2=giL[te*24+3*tid+2];
        float hj = (te>0)? hread(ldsp_h, j) : 0.f;
        float r_=sigm(gi0+gr), z_=sigm(gi1+gz);
        float n_=tanhf(gi2+r_*gn);
        float h2v=(1.f-z_)*n_+z_*hj;
        st_tag(&A.hbE[(te&1)*HDIM+j], h2v, (unsigned)((te+1)&31));
        st_tag(&A.enc_outs[te*HDIM+j], h2v, (unsigned)(te%31));
        if(te==LSEQ-1) st_tag(&A.hbD[j], h2v, 0u);
      }
      __syncthreads();
    }
    fence_vm();
    __syncthreads();
  } else {
    // ---- spectators (128): attn_e + pre_comb, then PIPELINED MT ----
    const int q = (bid<6)? bid : bid-128;   // 0..127
    PChunk wpc[2]; float bpc[2]; int ri[2];
    #pragma unroll
    for(int k=0;k<2;k++){
      ri[k] = q*8 + wave*2 + k;
      wpc[k] = load_pchunk(A.comb_W + (size_t)ri[k]*2*HDIM, lane);
      pinp(wpc[k]);
      bpc[k] = A.comb_b[ri[k]];
    }
    for(int t=0;t<LSEQ;++t){
      int tok = (t==0)?1:A.tag_ids[t-1];
      float ec[16]; load_vec16(A.dec_embed + (size_t)tok*HDIM, ec, lane);
      h2 ep[8]; pack16(ec, ep);
      float d[2] = {pdot(wpc[0],ep), pdot(wpc[1],ep)};
      wred_batch<2>(d);
      if(lane==0){
        st_coh(&A.pre_comb[t*HDIM+ri[0]], d[0]+bpc[0]);
        st_coh(&A.pre_comb[t*HDIM+ri[1]], d[1]+bpc[1]);
      }
    }
    if(q < LSEQ){
      PChunk wae = load_pchunk(A.attn_W + (size_t)q*2*HDIM, lane);
      float bae = A.attn_b[q];
      const int t0 = wave*13, tc = (wave<3)?13:11;
      for(int u=0;u<tc;++u){
        int t = t0+u;
        int tok = (t==0)?1:A.tag_ids[t-1];
        float ec[16]; load_vec16(A.dec_embed + (size_t)tok*HDIM, ec, lane);
        h2 ep[8]; pack16(ec, ep);
        float d = wred_sum(pdot(wae,ep));
        if(lane==0) st_coh(&A.attn_e[t*LSEQ+q], d+bae);
      }
    }
    // ---- MT pipeline: rows si and si+512, tracking the encoder ----
    {
      const int si = q*4 + wave;            // 0..511
      PChunk wm0 = load_pchunk(A.comb_W + (size_t)si*2*HDIM + HDIM, lane);
      pinp(wm0);
      PChunk wm1 = load_pchunk(A.comb_W + (size_t)(si+512)*2*HDIM + HDIM, lane);
      pinp(wm1);
      for(int s=0;s<LSEQ;++s){
        const unsigned tg = (unsigned)(s%31);
        const float* g = A.enc_outs + s*HDIM;
        wait2_enc(g, tg, lane);
        h2 ep[8]; load16_tag(g, tg, lane, ep);
        float dd[2] = {pdot(wm0,ep), pdot(wm1,ep)};
        wred_batch<2>(dd);
        if(lane==0){
          st_coh(&A.MT[s*HDIM+si],     dd[0]);
          st_coh(&A.MT[s*HDIM+si+512], dd[1]);
        }
      }
    }
    fence_vm();
    __syncthreads();
    if(tid==0) addc0(A.ctrM);
  }

  // ================= decoder: 50 steps, 2 hops, no global barriers ==========
  if(bid < 4){
    // o-WGs: redundant aw (13 pinned packed attn rows/wave) + o slice of 256.
    const int oi = bid*256 + tid;
    PChunk wa13[13];
    int srow[13];
    #pragma unroll
    for(int i=0;i<13;i++){
      int s = wave + 4*i; int sc = (s<LSEQ)? s : 0;
      wa13[i] = load_pchunk(A.attn_W + (size_t)sc*2*HDIM + HDIM, lane);
      pinp(wa13[i]);
      srow[i] = s;
    }
    // wait for all 128 spectators' MT
    if(wave==0){
      for(;;){
        unsigned v = (lane==0)? ldu(A.ctrM) : 128u;
        if(__all((int)(v>=128u))) break;
        __builtin_amdgcn_s_sleep(2);
      }
    }
    __syncthreads();
    unsigned mp[25];
    #pragma unroll
    for(int k=0;k<25;k++){
      mp[k] = pack2(A.MT[(2*k)*HDIM+oi], A.MT[(2*k+1)*HDIM+oi]);
      pin32(mp[k]);
    }
    for(int t=0;t<LSEQ;++t){
      const unsigned tg = (unsigned)(t&31);
      float ae[13];
      #pragma unroll
      for(int i=0;i<13;i++)
        ae[i] = (srow[i]<LSEQ)? A.attn_e[t*LSEQ+srow[i]] : 0.f;
      float pcv = A.pre_comb[t*HDIM+oi];
      stage_tag_p<1>(ldsp_h, A.hbD + (t%3)*HDIM, tid, tg);
      __syncthreads();
      h2 hp[8]; read8p(ldsp_h, hp, lane);
      float pl[13];
      #pragma unroll
      for(int i=0;i<13;i++) pl[i]=pdot(wa13[i],hp);
      wred_batch<13>(pl);
      if(lane==0){
        #pragma unroll
        for(int i=0;i<13;i++) if(srow[i]<LSEQ) smL[srow[i]]=pl[i]+ae[i];
      }
      __syncthreads();
      if(wave==0){
        float l = (lane<LSEQ)? smL[lane] : -1e30f;
        float m = wred_max(l);
        float pe = (lane<LSEQ)? expf(l-m) : 0.f;
        float ss = wred_sum(pe);
        if(lane<LSEQ) smA[lane] = pe/ss;
      }
      __syncthreads();
      if(tid<25) awpL[tid] = (h2){(_Float16)smA[2*tid],(_Float16)smA[2*tid+1]};
      __syncthreads();
      float acc = pcv;
      #pragma unroll
      for(int k=0;k<25;k++) acc = FDOT2(as_h2(mp[k]), awpL[k], acc);
      st_tag(&A.obD[(t&1)*HDIM+oi], fmaxf(acc,0.f), tg);
      __syncthreads();
    }
  } else if(bid == 4){
    // collect tagged logits, double log_softmax, out + loss
    float loss = 0.f;
    for(int t=0;t<LSEQ;++t){
      if(tid<32){
        const float* pp = A.logits + (t&1)*TDIM + 4*tid;
        const unsigned tg = (unsigned)(t&31);
        f32x4 v;
        for(;;){
          v = coh_load4(pp);
          unsigned m = ((__float_as_uint(v.x)&31u)^tg) | ((__float_as_uint(v.y)&31u)^tg)
                     | ((__float_as_uint(v.z)&31u)^tg) | ((__float_as_uint(v.w)&31u)^tg);
          if(m==0u) break;
          __builtin_amdgcn_s_sleep(2);
        }
        smL[4*tid]=v.x; smL[4*tid+1]=v.y; smL[4*tid+2]=v.z; smL[4*tid+3]=v.w;
      }
      __syncthreads();
      if(tid==0) stf(A.ctrV, (unsigned)(t+1));   // epoch t logits consumed
      if(wave==0){
        float l0=smL[lane], l1=smL[lane+64];
        float m  = wred_max(fmaxf(l0,l1));
        float pe = expf(l0-m)+expf(l1-m);
        float s1 = wred_sum(pe);
        float lse = m + logf(s1);
        float lp0 = l0-lse, lp1 = l1-lse;
        float m2  = wred_max(fmaxf(lp0,lp1));
        float p2  = expf(lp0-m2)+expf(lp1-m2);
        float s2  = wred_sum(p2);
        float lse2 = m2 + logf(s2);
        A.out[t*TDIM + lane]      = lp0;
        A.out[t*TDIM + 64 + lane] = lp1;
        int tg2 = A.tag_ids[t];
        float c = ((lane==tg2)?(lse2-lp0):0.f) + ((lane+64==tg2)?(lse2-lp1):0.f);
        c = wred_sum(c);
        if(tg2 != 0) loss += c;
      }
      __syncthreads();
    }
    if(tid==0) A.out[LSEQ*TDIM] = loss;
  } else if(is_prod){
    // producers: pinned packed wh + wi; stage h -> gh -> stage o -> gi -> h'
    PChunk whp[6], wip[6];
    #pragma unroll
    for(int i=0;i<6;i++){
      int r = wave + 4*i;
      int le=r/3, g=r-3*le, row=g*HDIM+base+le;
      whp[i] = load_pchunk(A.dec_Whh + (size_t)row*HDIM, lane);
      pinp(whp[i]);
      wip[i] = load_pchunk(A.dec_Wih + (size_t)row*HDIM, lane);
      pinp(wip[i]);
    }
    float dh0=A.dec_bhh[j8], dh1=A.dec_bhh[HDIM+j8], dh2=A.dec_bhh[2*HDIM+j8];
    float di0=A.dec_bih[j8], di1=A.dec_bih[HDIM+j8], di2=A.dec_bih[2*HDIM+j8];
    for(int t=0;t<LSEQ;++t){
      const unsigned tg = (unsigned)(t&31);
      stage_tag_p<1>(ldsp_h, A.hbD + (t%3)*HDIM, tid, tg);
      __syncthreads();
      h2 hp[8]; read8p(ldsp_h, hp, lane);
      float ph[6];
      #pragma unroll
      for(int i=0;i<6;i++) ph[i]=pdot(whp[i],hp);
      wred_batch<6>(ph);
      if(lane==0){
        #pragma unroll
        for(int i=0;i<6;i++) smr[wave+4*i]=ph[i];
      }
      // gate: out-proj WGs must have staged epoch t-2 before we clobber hbD
      if(wave==0 && t>=3){
        const unsigned tgt = 16u*(unsigned)(t-2);
        for(;;){
          unsigned v = (lane==0)? ldu(A.ctrO) : tgt;
          if(__all((int)(v>=tgt))) break;
          __builtin_amdgcn_s_sleep(2);
        }
      }
      stage_tag_p<1>(ldsp_o, A.obD + (t&1)*HDIM, tid, tg);
      __syncthreads();
      h2 op[8]; read8p(ldsp_o, op, lane);
      float po[6];
      #pragma unroll
      for(int i=0;i<6;i++) po[i]=pdot(wip[i],op);
      wred_batch<6>(po);
      if(lane==0){
        #pragma unroll
        for(int i=0;i<6;i++) smr[32+wave+4*i]=po[i];
      }
      __syncthreads();
      if(tid<8){
        int j = base+tid;
        float gr=smr[tid*3]+dh0,    gz=smr[tid*3+1]+dh1,    gn=smr[tid*3+2]+dh2;
        float ir=smr[32+tid*3]+di0, iz=smr[32+tid*3+1]+di1, inn=smr[32+tid*3+2]+di2;
        float hj = hread(ldsp_h, j);
        float r_=sigm(ir+gr), z_=sigm(iz+gz);
        float n_=tanhf(inn+r_*gn);
        float h2v=(1.f-z_)*n_+z_*hj;
        st_tag(&A.hbD[((t+1)%3)*HDIM+j], h2v, (unsigned)((t+1)&31));
      }
      __syncthreads();
    }
  } else if(bid>=134 && bid<150){
    // out-proj: 8 rows each, 2 rows/wave pinned packed
    const int ob = bid-134;
    PChunk wop[2];
    float bo[2];
    #pragma unroll
    for(int i=0;i<2;i++){
      int row = ob*8 + wave*2 + i;
      wop[i]=load_pchunk(A.out_W+(size_t)row*HDIM,lane);
      pinp(wop[i]);
      bo[i]=A.out_b[row];
    }
    for(int t=0;t<LSEQ;++t){
      const unsigned tg1 = (unsigned)((t+1)&31);
      stage_tag_p<2>(ldsp_h, A.hbD + ((t+1)%3)*HDIM, tid, tg1);
      __syncthreads();
      if(tid==0) addc0(A.ctrO);            // "I staged epoch t+1"
      h2 hp[8]; read8p(ldsp_h, hp, lane);
      float pt[2]={pdot(wop[0],hp),pdot(wop[1],hp)};
      wred_batch<2>(pt);
      if(wave==0 && t>=2){
        const unsigned tgt = (unsigned)(t-1);  // WG4 consumed epoch t-2
        for(;;){
          unsigned v = (lane==0)? ldu(A.ctrV) : tgt;
          if(__all((int)(v>=tgt))) break;
          __builtin_amdgcn_s_sleep(4);
        }
      }
      __syncthreads();
      if(lane==0){
        int row = ob*8 + wave*2;
        st_tag(&A.logits[(t&1)*TDIM + row],   pt[0]+bo[0], (unsigned)(t&31));
        st_tag(&A.logits[(t&1)*TDIM + row+1], pt[1]+bo[1], (unsigned)(t&31));
      }
      __syncthreads();
    }
  }
}

extern "C" void kernel_launch(void* const* d_in, const int* in_sizes, int n_in,
                              void* d_out, int out_size, void* d_ws, size_t ws_size,
                              hipStream_t stream){
  (void)in_sizes; (void)n_in; (void)out_size; (void)ws_size;
  KArgs A;
  A.input_ids = (const int*)d_in[0];
  A.tag_ids   = (const int*)d_in[1];
  A.word_embed= (const float*)d_in[2];
  A.enc_Wih   = (const float*)d_in[3];
  A.enc_Whh   = (const float*)d_in[4];
  A.enc_bih   = (const float*)d_in[5];
  A.enc_bhh   = (const float*)d_in[6];
  A.dec_embed = (const float*)d_in[7];
  A.attn_W    = (const float*)d_in[8];
  A.attn_b    = (const float*)d_in[9];
  A.comb_W    = (const float*)d_in[10];
  A.comb_b    = (const float*)d_in[11];
  A.dec_Wih   = (const float*)d_in[12];
  A.dec_Whh   = (const float*)d_in[13];
  A.dec_bih   = (const float*)d_in[14];
  A.dec_bhh   = (const float*)d_in[15];
  A.out_W     = (const float*)d_in[16];
  A.out_b     = (const float*)d_in[17];
  A.out       = (float*)d_out;

  unsigned* u = (unsigned*)d_ws;
  A.ctrM = u;          // single line
  A.ctrO = u + 64;     // single line
  A.ctrV = u + 128;    // single line
  float* f = (float*)d_ws + 1024;   // byte 4096, tagged region start
  A.hbE      = f; f += 2*HDIM;
  A.hbD      = f; f += 3*HDIM;
  A.obD      = f; f += 2*HDIM;
  A.logits   = f; f += 2*TDIM;
  A.enc_outs = f; f += LSEQ*HDIM;   // tagged region: 58624 floats
  A.attn_e   = f; f += LSEQ*LSEQ + 14;
  A.pre_comb = f; f += LSEQ*HDIM;
  A.MT       = f; f += LSEQ*HDIM;

  (void)hipMemsetAsync(d_ws, 0, 4096, stream);                        // counters
  (void)hipMemsetAsync((char*)d_ws + 4096, 0xFF, 58624*4, stream);    // tag bufs -> tag 31
  void* args[] = { &A };
  hipError_t err = hipLaunchCooperativeKernel((const void*)seq2seq_kernel,
                                              dim3(256), dim3(256), args, 0, stream);
  if(err != hipSuccess){
    // 256 WGs on 256 CUs are co-resident by capacity; cooperative API was
    // only belt-and-braces. Fall back to a normal launch.
    hipLaunchKernelGGL(seq2seq_kernel, dim3(256), dim3(256), 0, stream, A);
  }
}

// Round 15
// 457.426 us; speedup vs baseline: 1.4446x; 1.0031x over previous
//
#include <hip/hip_runtime.h>
#include <cstdint>

// Seq2Seq GRU enc/dec with attention, batch=1, L=50, H=1024, T=128 (fp32 in/out).
// Persistent cooperative kernel, 256 WGs x 256 threads.
// Sync: VALUE TAGS (low 5 mantissa bits = epoch); retry loads ARE the poll.
// Weights fp16-packed & pinned in VGPRs (v_dot2_f32_f16).
// R15 decoder: h -> WG0 (pinned attn -> aw, 52-float broadcast) -> producers
// (pinned wh+wi+M-columns: local o from aw, no 1024-float o hop) -> h'.
// Spectators compute attn_e/pre_comb (ctrA) then pipelined MT (ctrM) during
// the encoder; no global barriers anywhere.

#define HDIM 1024
#define LSEQ 50
#define TDIM 128
#define PB   6
#define NPROD 128
#define LSTRP 65

typedef float f32x4 __attribute__((ext_vector_type(4)));
typedef _Float16 h2 __attribute__((ext_vector_type(2)));

#if __has_builtin(__builtin_amdgcn_fdot2)
#define FDOT2(a,b,c) __builtin_amdgcn_fdot2((a),(b),(c),false)
#else
__device__ __forceinline__ float fdot2_sw(h2 a, h2 b, float c){
  return c + (float)a[0]*(float)b[0] + (float)a[1]*(float)b[1];
}
#define FDOT2(a,b,c) fdot2_sw((a),(b),(c))
#endif

struct KArgs {
  const int* input_ids; const int* tag_ids;
  const float* word_embed;
  const float* enc_Wih; const float* enc_Whh; const float* enc_bih; const float* enc_bhh;
  const float* dec_embed; const float* attn_W; const float* attn_b;
  const float* comb_W; const float* comb_b;
  const float* dec_Wih; const float* dec_Whh; const float* dec_bih; const float* dec_bhh;
  const float* out_W; const float* out_b;
  float* out;
  unsigned* ctrA; unsigned* ctrM; unsigned* ctrO; unsigned* ctrV;
  float* hbE;      // 2*1024 tagged
  float* hbD;      // 3*1024 tagged
  float* logits;   // 2*128  tagged
  float* awb;      // 2*64   tagged (52 used)
  float* enc_outs; // 50*1024 tagged (write-once, tag = te%31)
  float* attn_e;   // 50*50
  float* pre_comb; // 50*1024
  float* MT;       // 50*1024  (MT[s*H+i])
};

__device__ __forceinline__ void fence_vm(){
  asm volatile("s_waitcnt vmcnt(0)" ::: "memory");
}
__device__ __forceinline__ void st_coh(float* p, float v){
  __hip_atomic_store(p, v, __ATOMIC_RELAXED, __HIP_MEMORY_SCOPE_AGENT);
}
__device__ __forceinline__ void st_tag(float* p, float v, unsigned tag){
  unsigned b = (__float_as_uint(v) & ~31u) | tag;
  st_coh(p, __uint_as_float(b));
}
__device__ __forceinline__ void stf(unsigned* p, unsigned v){
  __hip_atomic_store(p, v, __ATOMIC_RELAXED, __HIP_MEMORY_SCOPE_AGENT);
}
__device__ __forceinline__ unsigned ldu(const unsigned* p){
  return __hip_atomic_load(p, __ATOMIC_RELAXED, __HIP_MEMORY_SCOPE_AGENT);
}
__device__ __forceinline__ void addc0(unsigned* base){
  __hip_atomic_fetch_add(base, 1u, __ATOMIC_RELAXED, __HIP_MEMORY_SCOPE_AGENT);
}
__device__ __forceinline__ f32x4 coh_load4(const float* p){
  f32x4 v;
  asm volatile("global_load_dwordx4 %0, %1, off sc0 sc1\n\ts_waitcnt vmcnt(0)"
               : "=v"(v) : "v"(p) : "memory");
  return v;
}

template<int N>
__device__ __forceinline__ void wred_batch(float* v){
  #pragma unroll
  for(int o=32;o>0;o>>=1){
    #pragma unroll
    for(int i=0;i<N;i++) v[i] += __shfl_xor(v[i],o,64);
  }
}
__device__ __forceinline__ float wred_sum(float v){
  #pragma unroll
  for(int o=32;o>0;o>>=1) v += __shfl_xor(v,o,64);
  return v;
}
__device__ __forceinline__ float wred_max(float v){
  #pragma unroll
  for(int o=32;o>0;o>>=1) v = fmaxf(v,__shfl_xor(v,o,64));
  return v;
}

__device__ __forceinline__ void load_vec16(const float* __restrict__ v, float* hc, int lane){
  const f32x4* p = reinterpret_cast<const f32x4*>(v) + lane*4;
  f32x4 x0=p[0],x1=p[1],x2=p[2],x3=p[3];
  hc[0]=x0.x; hc[1]=x0.y; hc[2]=x0.z; hc[3]=x0.w;
  hc[4]=x1.x; hc[5]=x1.y; hc[6]=x1.z; hc[7]=x1.w;
  hc[8]=x2.x; hc[9]=x2.y; hc[10]=x2.z; hc[11]=x2.w;
  hc[12]=x3.x; hc[13]=x3.y; hc[14]=x3.z; hc[15]=x3.w;
}

// ---- fp16-packed row chunk: 16 weights as 8 packed pairs (8 VGPRs) ----
struct PChunk { unsigned m[8]; };
__device__ __forceinline__ h2 as_h2(unsigned u){ return __builtin_bit_cast(h2, u); }
__device__ __forceinline__ unsigned as_u(h2 h){ return __builtin_bit_cast(unsigned, h); }
__device__ __forceinline__ unsigned pack2(float a, float b){
  return as_u((h2){(_Float16)a, (_Float16)b});
}
__device__ __forceinline__ PChunk load_pchunk(const float* __restrict__ row, int lane){
  const f32x4* p = reinterpret_cast<const f32x4*>(row) + lane*4;
  f32x4 a=p[0],b=p[1],c=p[2],d=p[3];
  PChunk w;
  w.m[0]=pack2(a.x,a.y); w.m[1]=pack2(a.z,a.w);
  w.m[2]=pack2(b.x,b.y); w.m[3]=pack2(b.z,b.w);
  w.m[4]=pack2(c.x,c.y); w.m[5]=pack2(c.z,c.w);
  w.m[6]=pack2(d.x,d.y); w.m[7]=pack2(d.z,d.w);
  return w;
}
__device__ __forceinline__ void pinp(PChunk& c){
  asm volatile("" : "+v"(c.m[0]),"+v"(c.m[1]),"+v"(c.m[2]),"+v"(c.m[3]),
                    "+v"(c.m[4]),"+v"(c.m[5]),"+v"(c.m[6]),"+v"(c.m[7]));
}
__device__ __forceinline__ void pin32(unsigned& x){ asm volatile("" : "+v"(x)); }
__device__ __forceinline__ float pdot(const PChunk& w, const h2* hp){
  float acc = 0.f;
  #pragma unroll
  for(int k=0;k<8;k++) acc = FDOT2(as_h2(w.m[k]), hp[k], acc);
  return acc;
}
__device__ __forceinline__ float sigm(float x){ return 1.f/(1.f+expf(-x)); }
__device__ __forceinline__ void pack16(const float* ec, h2* ep){
  #pragma unroll
  for(int k=0;k<8;k++) ep[k]=(h2){(_Float16)ec[2*k],(_Float16)ec[2*k+1]};
}

// retry-stage 1024 tagged fp32 -> packed fp16 LDS. Element j lives in pair
// pj=j>>1 at ldsp[(pj&7)*LSTRP + (pj>>3)].
template<int SLP>
__device__ __forceinline__ void stage_tag_p(h2* ldsp, const float* g, int tid, unsigned tag){
  const float* p = g + 4*tid;
  f32x4 v;
  for(;;){
    v = coh_load4(p);
    unsigned m = ((__float_as_uint(v.x)&31u)^tag) | ((__float_as_uint(v.y)&31u)^tag)
               | ((__float_as_uint(v.z)&31u)^tag) | ((__float_as_uint(v.w)&31u)^tag);
    if(m==0u) break;
    if(SLP) __builtin_amdgcn_s_sleep(SLP);
  }
  int q = tid>>2, m0 = (tid&3)*2;
  ldsp[m0*LSTRP+q]     = (h2){(_Float16)v.x,(_Float16)v.y};
  ldsp[(m0+1)*LSTRP+q] = (h2){(_Float16)v.z,(_Float16)v.w};
}
__device__ __forceinline__ void read8p(const h2* ldsp, h2* hp, int lane){
  #pragma unroll
  for(int k=0;k<8;k++) hp[k]=ldsp[k*LSTRP+lane];
}
__device__ __forceinline__ float hread(const h2* ldsp, int j){
  int pj = j>>1;
  h2 v = ldsp[(pj&7)*LSTRP + (pj>>3)];
  return (float)v[j&1];
}

// spectator MT-pipeline: cheap per-lane detect (two 4B tags)
__device__ __forceinline__ void wait2_enc(const float* g, unsigned tg, int lane){
  const float* p0 = g + lane*16 + 7;
  const float* p1 = g + lane*16 + 15;
  for(;;){
    float a,b;
    asm volatile("global_load_dword %0, %2, off sc0 sc1\n\t"
                 "global_load_dword %1, %3, off sc0 sc1\n\t"
                 "s_waitcnt vmcnt(0)"
                 : "=v"(a), "=v"(b) : "v"(p0), "v"(p1) : "memory");
    unsigned m = ((__float_as_uint(a)&31u)^tg) | ((__float_as_uint(b)&31u)^tg);
    if(__all((int)(m==0u))) return;
    __builtin_amdgcn_s_sleep(4);
  }
}
__device__ __forceinline__ void load16_tag(const float* g, unsigned tg, int lane, h2* ep){
  const float* p = g + lane*16;
  for(;;){
    f32x4 a=coh_load4(p), b=coh_load4(p+4), c=coh_load4(p+8), d=coh_load4(p+12);
    unsigned m = ((__float_as_uint(a.x)&31u)^tg)|((__float_as_uint(a.y)&31u)^tg)
               | ((__float_as_uint(a.z)&31u)^tg)|((__float_as_uint(a.w)&31u)^tg)
               | ((__float_as_uint(b.x)&31u)^tg)|((__float_as_uint(b.y)&31u)^tg)
               | ((__float_as_uint(b.z)&31u)^tg)|((__float_as_uint(b.w)&31u)^tg)
               | ((__float_as_uint(c.x)&31u)^tg)|((__float_as_uint(c.y)&31u)^tg)
               | ((__float_as_uint(c.z)&31u)^tg)|((__float_as_uint(c.w)&31u)^tg)
               | ((__float_as_uint(d.x)&31u)^tg)|((__float_as_uint(d.y)&31u)^tg)
               | ((__float_as_uint(d.z)&31u)^tg)|((__float_as_uint(d.w)&31u)^tg);
    if(m==0u){
      ep[0]=(h2){(_Float16)a.x,(_Float16)a.y}; ep[1]=(h2){(_Float16)a.z,(_Float16)a.w};
      ep[2]=(h2){(_Float16)b.x,(_Float16)b.y}; ep[3]=(h2){(_Float16)b.z,(_Float16)b.w};
      ep[4]=(h2){(_Float16)c.x,(_Float16)c.y}; ep[5]=(h2){(_Float16)c.z,(_Float16)c.w};
      ep[6]=(h2){(_Float16)d.x,(_Float16)d.y}; ep[7]=(h2){(_Float16)d.z,(_Float16)d.w};
      return;
    }
    __builtin_amdgcn_s_sleep(2);
  }
}
// wait a counter (single line) to reach n; wave0 lane0 polls
__device__ __forceinline__ void wait_ctr1(const unsigned* p, unsigned n, int lane){
  for(;;){
    unsigned v = (lane==0)? ldu(p) : n;
    if(__all((int)(v>=n))) return;
    __builtin_amdgcn_s_sleep(2);
  }
}

__global__ __launch_bounds__(256,1) void seq2seq_kernel(KArgs A){
  const int bid = blockIdx.x, tid = threadIdx.x;
  const int wave = tid>>6, lane = tid&63;
  __shared__ h2 ldsp_h[8*LSTRP+8];
  __shared__ h2 ldsp_o[8*LSTRP+8];
  __shared__ h2 awpL[32];
  __shared__ float smr[64];
  __shared__ float smL[TDIM];
  __shared__ float smA[64];
  __shared__ float giL[LSEQ*24];

  // producer geometry: bids 6..133 own 8 h-elements each
  const int p = bid - PB;
  const bool is_prod = (p>=0 && p<NPROD);
  const int base = is_prod ? p*8 : 0;
  const int j8 = base + (tid&7);

  // ================= phase A (no global barrier) ============================
  if(is_prod){
    {
      PChunk wgi[6]; float bgi[6];
      #pragma unroll
      for(int i=0;i<6;i++){
        int r = wave + 4*i;
        int le=r/3, g=r-3*le, grow=g*HDIM+base+le;
        wgi[i] = load_pchunk(A.enc_Wih + (size_t)grow*HDIM, lane);
        pinp(wgi[i]);
        bgi[i] = A.enc_bih[grow];
      }
      for(int te=0;te<LSEQ;++te){
        int tok = A.input_ids[te];
        float ec[16]; load_vec16(A.word_embed + (size_t)tok*HDIM, ec, lane);
        h2 ep[8]; pack16(ec, ep);
        float d[6];
        #pragma unroll
        for(int i=0;i<6;i++) d[i]=pdot(wgi[i],ep);
        wred_batch<6>(d);
        if(lane==0){
          #pragma unroll
          for(int i=0;i<6;i++) giL[te*24 + wave+4*i] = d[i]+bgi[i];
        }
      }
      __syncthreads();
    }
    PChunk wep[6];
    #pragma unroll
    for(int i=0;i<6;i++){
      int r = wave + 4*i;
      int le=r/3, g=r-3*le, row=g*HDIM+base+le;
      wep[i] = load_pchunk(A.enc_Whh + (size_t)row*HDIM, lane);
      pinp(wep[i]);
    }
    float bh0=A.enc_bhh[j8], bh1=A.enc_bhh[HDIM+j8], bh2=A.enc_bhh[2*HDIM+j8];
    for(int te=0;te<LSEQ;++te){
      h2 hp[8];
      if(te>0){
        stage_tag_p<1>(ldsp_h, A.hbE + ((te-1)&1)*HDIM, tid, (unsigned)(te&31));
        __syncthreads();
        read8p(ldsp_h, hp, lane);
      } else {
        #pragma unroll
        for(int k=0;k<8;k++) hp[k]=(h2){(_Float16)0.f,(_Float16)0.f};
      }
      float part[6];
      #pragma unroll
      for(int i=0;i<6;i++) part[i]=pdot(wep[i],hp);
      wred_batch<6>(part);
      if(lane==0){
        #pragma unroll
        for(int i=0;i<6;i++) smr[wave+4*i]=part[i];
      }
      __syncthreads();
      if(tid<8){
        int j = base+tid;
        float gr=smr[tid*3]+bh0, gz=smr[tid*3+1]+bh1, gn=smr[tid*3+2]+bh2;
        float gi0=giL[te*24+3*tid], gi1=giL[te*24+3*tid+1], gi2=giL[te*24+3*tid+2];
        float hj = (te>0)? hread(ldsp_h, j) : 0.f;
        float r_=sigm(gi0+gr), z_=sigm(gi1+gz);
        float n_=tanhf(gi2+r_*gn);
        float h2v=(1.f-z_)*n_+z_*hj;
        st_tag(&A.hbE[(te&1)*HDIM+j], h2v, (unsigned)((te+1)&31));
        st_tag(&A.enc_outs[te*HDIM+j], h2v, (unsigned)(te%31));
        if(te==LSEQ-1) st_tag(&A.hbD[j], h2v, 0u);
      }
      __syncthreads();
    }
    fence_vm();
    __syncthreads();
  } else {
    // ---- spectators (128): attn_e + pre_comb (ctrA), then pipelined MT (ctrM)
    const int q = (bid<6)? bid : bid-128;   // 0..127
    PChunk wpc[2]; float bpc[2]; int ri[2];
    #pragma unroll
    for(int k=0;k<2;k++){
      ri[k] = q*8 + wave*2 + k;
      wpc[k] = load_pchunk(A.comb_W + (size_t)ri[k]*2*HDIM, lane);
      pinp(wpc[k]);
      bpc[k] = A.comb_b[ri[k]];
    }
    for(int t=0;t<LSEQ;++t){
      int tok = (t==0)?1:A.tag_ids[t-1];
      float ec[16]; load_vec16(A.dec_embed + (size_t)tok*HDIM, ec, lane);
      h2 ep[8]; pack16(ec, ep);
      float d[2] = {pdot(wpc[0],ep), pdot(wpc[1],ep)};
      wred_batch<2>(d);
      if(lane==0){
        st_coh(&A.pre_comb[t*HDIM+ri[0]], d[0]+bpc[0]);
        st_coh(&A.pre_comb[t*HDIM+ri[1]], d[1]+bpc[1]);
      }
    }
    if(q < LSEQ){
      PChunk wae = load_pchunk(A.attn_W + (size_t)q*2*HDIM, lane);
      float bae = A.attn_b[q];
      const int t0 = wave*13, tc = (wave<3)?13:11;
      for(int u=0;u<tc;++u){
        int t = t0+u;
        int tok = (t==0)?1:A.tag_ids[t-1];
        float ec[16]; load_vec16(A.dec_embed + (size_t)tok*HDIM, ec, lane);
        h2 ep[8]; pack16(ec, ep);
        float d = wred_sum(pdot(wae,ep));
        if(lane==0) st_coh(&A.attn_e[t*LSEQ+q], d+bae);
      }
    }
    fence_vm();
    __syncthreads();
    if(tid==0) addc0(A.ctrA);
    // ---- MT pipeline: rows si and si+512, tracking the encoder ----
    {
      const int si = q*4 + wave;
      PChunk wm0 = load_pchunk(A.comb_W + (size_t)si*2*HDIM + HDIM, lane);
      pinp(wm0);
      PChunk wm1 = load_pchunk(A.comb_W + (size_t)(si+512)*2*HDIM + HDIM, lane);
      pinp(wm1);
      for(int s=0;s<LSEQ;++s){
        const unsigned tg = (unsigned)(s%31);
        const float* g = A.enc_outs + s*HDIM;
        wait2_enc(g, tg, lane);
        h2 ep[8]; load16_tag(g, tg, lane, ep);
        float dd[2] = {pdot(wm0,ep), pdot(wm1,ep)};
        wred_batch<2>(dd);
        if(lane==0){
          st_coh(&A.MT[s*HDIM+si],     dd[0]);
          st_coh(&A.MT[s*HDIM+si+512], dd[1]);
        }
      }
    }
    fence_vm();
    __syncthreads();
    if(tid==0) addc0(A.ctrM);
  }

  // ================= decoder: 50 steps ======================================
  if(bid == 0){
    // attn WG: 13 pinned packed attn_W[:,H:] rows per wave -> aw broadcast
    PChunk wa13[13];
    int srow[13];
    #pragma unroll
    for(int i=0;i<13;i++){
      int s = wave + 4*i; int sc = (s<LSEQ)? s : 0;
      wa13[i] = load_pchunk(A.attn_W + (size_t)sc*2*HDIM + HDIM, lane);
      pinp(wa13[i]);
      srow[i] = s;
    }
    if(wave==0) wait_ctr1(A.ctrA, 128u, lane);
    __syncthreads();
    for(int t=0;t<LSEQ;++t){
      const unsigned tg = (unsigned)(t&31);
      float ae[13];
      #pragma unroll
      for(int i=0;i<13;i++)
        ae[i] = (srow[i]<LSEQ)? A.attn_e[t*LSEQ+srow[i]] : 0.f;
      stage_tag_p<0>(ldsp_h, A.hbD + (t%3)*HDIM, tid, tg);
      __syncthreads();
      h2 hp[8]; read8p(ldsp_h, hp, lane);
      float pl[13];
      #pragma unroll
      for(int i=0;i<13;i++) pl[i]=pdot(wa13[i],hp);
      wred_batch<13>(pl);
      if(lane==0){
        #pragma unroll
        for(int i=0;i<13;i++) if(srow[i]<LSEQ) smL[srow[i]]=pl[i]+ae[i];
      }
      __syncthreads();
      if(wave==0){
        float l = (lane<LSEQ)? smL[lane] : -1e30f;
        float m = wred_max(l);
        float pe = (lane<LSEQ)? expf(l-m) : 0.f;
        float ss = wred_sum(pe);
        float av = (lane<LSEQ)? pe/ss : 0.f;
        if(lane<52) st_tag(&A.awb[(t&1)*64+lane], av, tg);
      }
      __syncthreads();
    }
  } else if(bid == 4){
    // collect tagged logits, double log_softmax, out + loss
    float loss = 0.f;
    for(int t=0;t<LSEQ;++t){
      if(tid<32){
        const float* pp = A.logits + (t&1)*TDIM + 4*tid;
        const unsigned tg = (unsigned)(t&31);
        f32x4 v;
        for(;;){
          v = coh_load4(pp);
          unsigned m = ((__float_as_uint(v.x)&31u)^tg) | ((__float_as_uint(v.y)&31u)^tg)
                     | ((__float_as_uint(v.z)&31u)^tg) | ((__float_as_uint(v.w)&31u)^tg);
          if(m==0u) break;
          __builtin_amdgcn_s_sleep(2);
        }
        smL[4*tid]=v.x; smL[4*tid+1]=v.y; smL[4*tid+2]=v.z; smL[4*tid+3]=v.w;
      }
      __syncthreads();
      if(tid==0) stf(A.ctrV, (unsigned)(t+1));
      if(wave==0){
        float l0=smL[lane], l1=smL[lane+64];
        float m  = wred_max(fmaxf(l0,l1));
        float pe = expf(l0-m)+expf(l1-m);
        float s1 = wred_sum(pe);
        float lse = m + logf(s1);
        float lp0 = l0-lse, lp1 = l1-lse;
        float m2  = wred_max(fmaxf(lp0,lp1));
        float p2  = expf(lp0-m2)+expf(lp1-m2);
        float s2  = wred_sum(p2);
        float lse2 = m2 + logf(s2);
        A.out[t*TDIM + lane]      = lp0;
        A.out[t*TDIM + 64 + lane] = lp1;
        int tg2 = A.tag_ids[t];
        float c = ((lane==tg2)?(lse2-lp0):0.f) + ((lane+64==tg2)?(lse2-lp1):0.f);
        c = wred_sum(c);
        if(tg2 != 0) loss += c;
      }
      __syncthreads();
    }
    if(tid==0) A.out[LSEQ*TDIM] = loss;
  } else if(is_prod){
    // producers: pinned wh+wi + 100 pinned M-coeffs; o computed locally
    PChunk whp[6], wip[6];
    #pragma unroll
    for(int i=0;i<6;i++){
      int r = wave + 4*i;
      int le=r/3, g=r-3*le, row=g*HDIM+base+le;
      whp[i] = load_pchunk(A.dec_Whh + (size_t)row*HDIM, lane);
      pinp(whp[i]);
      wip[i] = load_pchunk(A.dec_Wih + (size_t)row*HDIM, lane);
      pinp(wip[i]);
    }
    float dh0=A.dec_bhh[j8], dh1=A.dec_bhh[HDIM+j8], dh2=A.dec_bhh[2*HDIM+j8];
    float di0=A.dec_bih[j8], di1=A.dec_bih[HDIM+j8], di2=A.dec_bih[2*HDIM+j8];
    if(wave==0) wait_ctr1(A.ctrM, 128u, lane);
    __syncthreads();
    unsigned mp0[25], mp1[25], mp2[25], mp3[25];
    {
      const int j0 = 4*tid;
      #pragma unroll
      for(int k=0;k<25;k++){
        mp0[k]=pack2(A.MT[(2*k)*HDIM+j0  ], A.MT[(2*k+1)*HDIM+j0  ]); pin32(mp0[k]);
        mp1[k]=pack2(A.MT[(2*k)*HDIM+j0+1], A.MT[(2*k+1)*HDIM+j0+1]); pin32(mp1[k]);
        mp2[k]=pack2(A.MT[(2*k)*HDIM+j0+2], A.MT[(2*k+1)*HDIM+j0+2]); pin32(mp2[k]);
        mp3[k]=pack2(A.MT[(2*k)*HDIM+j0+3], A.MT[(2*k+1)*HDIM+j0+3]); pin32(mp3[k]);
      }
    }
    const f32x4* PC4 = reinterpret_cast<const f32x4*>(A.pre_comb);
    for(int t=0;t<LSEQ;++t){
      const unsigned tg = (unsigned)(t&31);
      f32x4 pc = PC4[t*256+tid];
      stage_tag_p<1>(ldsp_h, A.hbD + (t%3)*HDIM, tid, tg);
      __syncthreads();
      h2 hp[8]; read8p(ldsp_h, hp, lane);
      float ph[6];
      #pragma unroll
      for(int i=0;i<6;i++) ph[i]=pdot(whp[i],hp);
      wred_batch<6>(ph);
      if(lane==0){
        #pragma unroll
        for(int i=0;i<6;i++) smr[wave+4*i]=ph[i];
      }
      // gate: out-proj must have staged epoch t-2 before we clobber hbD
      if(wave==0 && t>=3){
        const unsigned tgt = 16u*(unsigned)(t-2);
        for(;;){
          unsigned v = (lane==0)? ldu(A.ctrO) : tgt;
          if(__all((int)(v>=tgt))) break;
          __builtin_amdgcn_s_sleep(2);
        }
      }
      // fetch 52-float aw line (retry-tagged), broadcast via LDS
      if(tid<13){
        const float* pp = A.awb + (t&1)*64 + 4*tid;
        f32x4 v;
        for(;;){
          v = coh_load4(pp);
          unsigned m = ((__float_as_uint(v.x)&31u)^tg) | ((__float_as_uint(v.y)&31u)^tg)
                     | ((__float_as_uint(v.z)&31u)^tg) | ((__float_as_uint(v.w)&31u)^tg);
          if(m==0u) break;
          __builtin_amdgcn_s_sleep(1);
        }
        smA[4*tid]=v.x; smA[4*tid+1]=v.y; smA[4*tid+2]=v.z; smA[4*tid+3]=v.w;
      }
      __syncthreads();
      if(tid<25) awpL[tid] = (h2){(_Float16)smA[2*tid],(_Float16)smA[2*tid+1]};
      __syncthreads();
      // local o: elements 4*tid..4*tid+3
      {
        float o0=pc.x, o1=pc.y, o2=pc.z, o3=pc.w;
        #pragma unroll
        for(int k=0;k<25;k++){
          h2 aw = awpL[k];
          o0 = FDOT2(as_h2(mp0[k]), aw, o0);
          o1 = FDOT2(as_h2(mp1[k]), aw, o1);
          o2 = FDOT2(as_h2(mp2[k]), aw, o2);
          o3 = FDOT2(as_h2(mp3[k]), aw, o3);
        }
        int q = tid>>2, m0 = (tid&3)*2;
        ldsp_o[m0*LSTRP+q]     = (h2){(_Float16)fmaxf(o0,0.f),(_Float16)fmaxf(o1,0.f)};
        ldsp_o[(m0+1)*LSTRP+q] = (h2){(_Float16)fmaxf(o2,0.f),(_Float16)fmaxf(o3,0.f)};
      }
      __syncthreads();
      h2 op[8]; read8p(ldsp_o, op, lane);
      float po[6];
      #pragma unroll
      for(int i=0;i<6;i++) po[i]=pdot(wip[i],op);
      wred_batch<6>(po);
      if(lane==0){
        #pragma unroll
        for(int i=0;i<6;i++) smr[32+wave+4*i]=po[i];
      }
      __syncthreads();
      if(tid<8){
        int j = base+tid;
        float gr=smr[tid*3]+dh0,    gz=smr[tid*3+1]+dh1,    gn=smr[tid*3+2]+dh2;
        float ir=smr[32+tid*3]+di0, iz=smr[32+tid*3+1]+di1, inn=smr[32+tid*3+2]+di2;
        float hj = hread(ldsp_h, j);
        float r_=sigm(ir+gr), z_=sigm(iz+gz);
        float n_=tanhf(inn+r_*gn);
        float h2v=(1.f-z_)*n_+z_*hj;
        st_tag(&A.hbD[((t+1)%3)*HDIM+j], h2v, (unsigned)((t+1)&31));
      }
      __syncthreads();
    }
  } else if(bid>=134 && bid<150){
    // out-proj: 8 rows each, 2 rows/wave pinned packed
    const int ob = bid-134;
    PChunk wop[2];
    float bo[2];
    #pragma unroll
    for(int i=0;i<2;i++){
      int row = ob*8 + wave*2 + i;
      wop[i]=load_pchunk(A.out_W+(size_t)row*HDIM,lane);
      pinp(wop[i]);
      bo[i]=A.out_b[row];
    }
    for(int t=0;t<LSEQ;++t){
      const unsigned tg1 = (unsigned)((t+1)&31);
      stage_tag_p<2>(ldsp_h, A.hbD + ((t+1)%3)*HDIM, tid, tg1);
      __syncthreads();
      if(tid==0) addc0(A.ctrO);
      h2 hp[8]; read8p(ldsp_h, hp, lane);
      float pt[2]={pdot(wop[0],hp),pdot(wop[1],hp)};
      wred_batch<2>(pt);
      if(wave==0 && t>=2){
        const unsigned tgt = (unsigned)(t-1);
        for(;;){
          unsigned v = (lane==0)? ldu(A.ctrV) : tgt;
          if(__all((int)(v>=tgt))) break;
          __builtin_amdgcn_s_sleep(4);
        }
      }
      __syncthreads();
      if(lane==0){
        int row = ob*8 + wave*2;
        st_tag(&A.logits[(t&1)*TDIM + row],   pt[0]+bo[0], (unsigned)(t&31));
        st_tag(&A.logits[(t&1)*TDIM + row+1], pt[1]+bo[1], (unsigned)(t&31));
      }
      __syncthreads();
    }
  }
}

extern "C" void kernel_launch(void* const* d_in, const int* in_sizes, int n_in,
                              void* d_out, int out_size, void* d_ws, size_t ws_size,
                              hipStream_t stream){
  (void)in_sizes; (void)n_in; (void)out_size; (void)ws_size;
  KArgs A;
  A.input_ids = (const int*)d_in[0];
  A.tag_ids   = (const int*)d_in[1];
  A.word_embed= (const float*)d_in[2];
  A.enc_Wih   = (const float*)d_in[3];
  A.enc_Whh   = (const float*)d_in[4];
  A.enc_bih   = (const float*)d_in[5];
  A.enc_bhh   = (const float*)d_in[6];
  A.dec_embed = (const float*)d_in[7];
  A.attn_W    = (const float*)d_in[8];
  A.attn_b    = (const float*)d_in[9];
  A.comb_W    = (const float*)d_in[10];
  A.comb_b    = (const float*)d_in[11];
  A.dec_Wih   = (const float*)d_in[12];
  A.dec_Whh   = (const float*)d_in[13];
  A.dec_bih   = (const float*)d_in[14];
  A.dec_bhh   = (const float*)d_in[15];
  A.out_W     = (const float*)d_in[16];
  A.out_b     = (const float*)d_in[17];
  A.out       = (float*)d_out;

  unsigned* u = (unsigned*)d_ws;
  A.ctrA = u;          // single line
  A.ctrM = u + 64;
  A.ctrO = u + 128;
  A.ctrV = u + 192;
  float* f = (float*)d_ws + 1024;   // byte 4096, tagged region start
  A.hbE      = f; f += 2*HDIM;
  A.hbD      = f; f += 3*HDIM;
  A.logits   = f; f += 2*TDIM;
  A.awb      = f; f += 2*64;
  A.enc_outs = f; f += LSEQ*HDIM;   // tagged region: 56704 floats
  A.attn_e   = f; f += LSEQ*LSEQ + 14;
  A.pre_comb = f; f += LSEQ*HDIM;
  A.MT       = f; f += LSEQ*HDIM;

  (void)hipMemsetAsync(d_ws, 0, 4096, stream);                        // counters
  (void)hipMemsetAsync((char*)d_ws + 4096, 0xFF, 56704*4, stream);    // tag bufs -> tag 31
  void* args[] = { &A };
  hipError_t err = hipLaunchCooperativeKernel((const void*)seq2seq_kernel,
                                              dim3(256), dim3(256), args, 0, stream);
  if(err != hipSuccess){
    // 256 WGs on 256 CUs are co-resident by capacity; cooperative API was
    // only belt-and-braces. Fall back to a normal launch.
    hipLaunchKernelGGL(seq2seq_kernel, dim3(256), dim3(256), 0, stream, A);
  }
}